// Round 3
// baseline (862.479 us; speedup 1.0000x reference)
//
#include <hip/hip_runtime.h>
#include <hip/hip_bf16.h>

typedef short bf16x8 __attribute__((ext_vector_type(8)));
typedef float f32x4 __attribute__((ext_vector_type(4)));

static inline int cdiv(int a, int b){ return (a + b - 1) / b; }

// ---------------- init: deg=1.0 (3N), cnt=0 (N) ----------------
__global__ void k_init(float* __restrict__ deg, int* __restrict__ cnt, int N){
    int i = blockIdx.x * 256 + threadIdx.x;
    if (i < 3 * N) deg[i] = 1.0f;
    if (i < N)     cnt[i] = 0;
}

// ---------------- deg accumulation + target count ----------------
__global__ void k_degcnt(const int* __restrict__ tgt,
                         const float* __restrict__ asp,
                         const float* __restrict__ actx,
                         const float* __restrict__ alat,
                         const float* __restrict__ wsp,
                         const float* __restrict__ wctx,
                         const float* __restrict__ wlat,
                         float* __restrict__ deg, int* __restrict__ cnt,
                         int N, int E){
    int e = blockIdx.x * 256 + threadIdx.x;
    if (e >= E) return;
    int t = tgt[e];
    atomicAdd(&deg[t],         asp[e]  * wsp[e]);
    atomicAdd(&deg[N + t],     actx[e] * wctx[e]);
    atomicAdd(&deg[2 * N + t], alat[e] * wlat[e]);
    atomicAdd(&cnt[t], 1);
}

// ---------------- 3-kernel exclusive scan over cnt[N] -> rs ----------------
__global__ void k_scan1(const int* __restrict__ cnt, int* __restrict__ rs,
                        int* __restrict__ bsum, int N){
    __shared__ int s[256];
    int i = blockIdx.x * 256 + threadIdx.x;
    int v = (i < N) ? cnt[i] : 0;
    s[threadIdx.x] = v;
    __syncthreads();
    for (int off = 1; off < 256; off <<= 1){
        int t = (threadIdx.x >= off) ? s[threadIdx.x - off] : 0;
        __syncthreads();
        s[threadIdx.x] += t;
        __syncthreads();
    }
    if (i < N) rs[i] = s[threadIdx.x] - v;      // exclusive
    if (threadIdx.x == 255) bsum[blockIdx.x] = s[255];
}

__global__ void k_scan2(int* __restrict__ bsum, int nb){  // nb <= 256 (N <= 65536)
    __shared__ int s[256];
    int v = (threadIdx.x < nb) ? bsum[threadIdx.x] : 0;
    s[threadIdx.x] = v;
    __syncthreads();
    for (int off = 1; off < 256; off <<= 1){
        int t = (threadIdx.x >= off) ? s[threadIdx.x - off] : 0;
        __syncthreads();
        s[threadIdx.x] += t;
        __syncthreads();
    }
    if (threadIdx.x < nb) bsum[threadIdx.x] = s[threadIdx.x] - v;  // exclusive
}

__global__ void k_scan3(int* __restrict__ rs, const int* __restrict__ bsum,
                        int N, int E){
    int i = blockIdx.x * 256 + threadIdx.x;
    if (i < N) rs[i] += bsum[blockIdx.x];
    if (i == 0) rs[N] = E;
}

__global__ void k_nextcpy(const int* __restrict__ rs, int* __restrict__ nxt, int N){
    int i = blockIdx.x * 256 + threadIdx.x;
    if (i < N) nxt[i] = rs[i];
}

__global__ void k_scatter(const int* __restrict__ tgt, int* __restrict__ nxt,
                          int* __restrict__ eord, int E){
    int e = blockIdx.x * 256 + threadIdx.x;
    if (e >= E) return;
    int pos = atomicAdd(&nxt[tgt[e]], 1);
    eord[pos] = e;
}

// ---------------- dinv = clip(deg,1e-6)^p_c  (per layer) ----------------
__global__ void k_dinv(const float* __restrict__ deg,
                       const float* __restrict__ dp,  // deg_power + l*3
                       float* __restrict__ dinv, int N){
    int i = blockIdx.x * 256 + threadIdx.x;
    if (i >= 3 * N) return;
    int c = i / N;
    float p = dp[c];
    float d = fmaxf(deg[i], 1e-6f);
    dinv[i] = powf(d, p);
}

// ---------------- norm[3e+c] = eff_c * dinv_c[tgt] * dinv_c[src] ----------------
__global__ void k_norm(const int* __restrict__ src, const int* __restrict__ tgt,
                       const float* __restrict__ asp,
                       const float* __restrict__ actx,
                       const float* __restrict__ alat,
                       const float* __restrict__ wsp,
                       const float* __restrict__ wctx,
                       const float* __restrict__ wlat,
                       const float* __restrict__ dinv,
                       float* __restrict__ normv, int N, int E){
    int e = blockIdx.x * 256 + threadIdx.x;
    if (e >= E) return;
    int s = src[e], t = tgt[e];
    float e0 = asp[e]  * wsp[e];
    float e1 = actx[e] * wctx[e];
    float e2 = alat[e] * wlat[e];
    normv[3 * e + 0] = e0 * dinv[t]         * dinv[s];
    normv[3 * e + 1] = e1 * dinv[N + t]     * dinv[N + s];
    normv[3 * e + 2] = e2 * dinv[2 * N + t] * dinv[2 * N + s];
}

// ---------------- x (fp32) -> xb (bf16) ----------------
__global__ void k_x2bf(const float* __restrict__ x, __hip_bfloat16* __restrict__ xb, int n){
    int i = blockIdx.x * 256 + threadIdx.x;
    if (i < n) xb[i] = __float2bfloat16(x[i]);
}

// ---------------- build BT[512][128] = [W_self | W3[0..2]] transposed, fp32->bf16 ----
__global__ void k_wcat(const float* __restrict__ Wself,  // [128,128] (k,j)
                       const float* __restrict__ W3,     // [3,128,128]
                       __hip_bfloat16* __restrict__ BT){ // [512,128] (j,k)
    int i = blockIdx.x * 256 + threadIdx.x;  // 65536
    int j = i >> 7, k = i & 127;
    float v;
    if (j < 128) v = Wself[k * 128 + j];
    else {
        int c = (j >> 7) - 1, jj = j & 127;
        v = W3[(c * 128 + k) * 128 + jj];
    }
    BT[i] = __float2bfloat16(v);
}

// ---------------- GEMM: C[M,512] = A[M,128] @ B[128,512] (B given transposed) ----
// nb==0 cols -> outbuf (fp32, +bias);  nb 1..3 -> Hbuf (bf16, channel nb-1)
__global__ __launch_bounds__(256) void k_gemm(
        const __hip_bfloat16* __restrict__ A,   // [M,128] bf16
        const __hip_bfloat16* __restrict__ BT,  // [512,128] bf16
        const float* __restrict__ bias,         // [128] fp32
        float* __restrict__ outbuf,             // [M,128]
        __hip_bfloat16* __restrict__ Hbuf,      // [M,384]
        int M){
    __shared__ __hip_bfloat16 As[128 * 128];
    __shared__ __hip_bfloat16 Bs[128 * 128];
    const int tid = threadIdx.x;
    const int mb = blockIdx.x, nb = blockIdx.y;
    const int row0 = mb * 128;

    // stage: 16B chunks, XOR-swizzled by (row&15) to kill bank conflicts
    #pragma unroll
    for (int it = 0; it < 8; ++it){
        int v = it * 256 + tid;
        int r = v >> 4, c = v & 15;
        int soff = r * 128 + (((c) ^ (r & 15)) << 3);
        int4 av = {0, 0, 0, 0};
        if (row0 + r < M)
            av = *(const int4*)(A + (size_t)(row0 + r) * 128 + (c << 3));
        *(int4*)(&As[soff]) = av;
        int4 bv = *(const int4*)(BT + (size_t)(nb * 128 + r) * 128 + (c << 3));
        *(int4*)(&Bs[soff]) = bv;
    }
    __syncthreads();

    const int w = tid >> 6, lane = tid & 63;
    const int wm = (w & 1) * 64, wn = (w >> 1) * 64;
    const int lm = lane & 15, lq = lane >> 4;

    f32x4 acc[4][4];
    #pragma unroll
    for (int mt = 0; mt < 4; ++mt)
        #pragma unroll
        for (int nt = 0; nt < 4; ++nt)
            acc[mt][nt] = {0.f, 0.f, 0.f, 0.f};

    #pragma unroll
    for (int kk = 0; kk < 4; ++kk){
        int kc = kk * 4 + lq;  // 16B-chunk index along K
        bf16x8 a[4], b[4];
        #pragma unroll
        for (int mt = 0; mt < 4; ++mt){
            int r = wm + mt * 16 + lm;
            a[mt] = *(const bf16x8*)(&As[r * 128 + ((kc ^ (r & 15)) << 3)]);
        }
        #pragma unroll
        for (int nt = 0; nt < 4; ++nt){
            int r = wn + nt * 16 + lm;
            b[nt] = *(const bf16x8*)(&Bs[r * 128 + ((kc ^ (r & 15)) << 3)]);
        }
        #pragma unroll
        for (int mt = 0; mt < 4; ++mt)
            #pragma unroll
            for (int nt = 0; nt < 4; ++nt)
                acc[mt][nt] = __builtin_amdgcn_mfma_f32_16x16x32_bf16(
                    a[mt], b[nt], acc[mt][nt], 0, 0, 0);
    }

    // epilogue: D[row = (lane>>4)*4 + reg][col = lane&15]
    #pragma unroll
    for (int mt = 0; mt < 4; ++mt){
        #pragma unroll
        for (int nt = 0; nt < 4; ++nt){
            #pragma unroll
            for (int r = 0; r < 4; ++r){
                int row = row0 + wm + mt * 16 + lq * 4 + r;
                int col = wn + nt * 16 + lm;
                if (row < M){
                    float v = acc[mt][nt][r];
                    if (nb == 0)
                        outbuf[(size_t)row * 128 + col] = v + bias[col];
                    else
                        Hbuf[(size_t)row * 384 + (nb - 1) * 128 + col] = __float2bfloat16(v);
                }
            }
        }
    }
}

// ---------------- message passing: one wave per target, no atomics ----------------
__global__ __launch_bounds__(256) void k_msg(
        float* __restrict__ outbuf,              // [N,128] (has self+bias)
        const __hip_bfloat16* __restrict__ Hbuf, // [N,384]
        const float* __restrict__ normv,         // [E*3]
        const int* __restrict__ src,
        const int* __restrict__ eord,
        const int* __restrict__ rs, int N){
    int w = threadIdx.x >> 6, lane = threadIdx.x & 63;
    int t = blockIdx.x * 4 + w;
    if (t >= N) return;
    float* op = outbuf + (size_t)t * 128 + lane * 2;
    float accx = op[0], accy = op[1];
    int beg = rs[t], end = rs[t + 1];
    for (int i = beg; i < end; ++i){
        int e = eord[i];
        int s = src[e];
        float n0 = normv[3 * e], n1 = normv[3 * e + 1], n2 = normv[3 * e + 2];
        const __hip_bfloat162* h = (const __hip_bfloat162*)(Hbuf + (size_t)s * 384);
        float2 h0 = __bfloat1622float2(h[lane]);
        float2 h1 = __bfloat1622float2(h[64 + lane]);
        float2 h2 = __bfloat1622float2(h[128 + lane]);
        accx += n0 * h0.x + n1 * h1.x + n2 * h2.x;
        accy += n0 * h0.y + n1 * h1.y + n2 * h2.y;
    }
    op[0] = accx; op[1] = accy;
}

// ---------------- LayerNorm + ReLU -> bf16 xnext (one wave per row) ----------------
__global__ __launch_bounds__(256) void k_ln(
        const float* __restrict__ outbuf,
        const float* __restrict__ g,
        const float* __restrict__ b,
        __hip_bfloat16* __restrict__ xnext, int N){
    int w = threadIdx.x >> 6, lane = threadIdx.x & 63;
    int t = blockIdx.x * 4 + w;
    if (t >= N) return;
    const float* row = outbuf + (size_t)t * 128;
    float x0 = row[2 * lane], x1 = row[2 * lane + 1];
    float s = x0 + x1;
    #pragma unroll
    for (int off = 32; off; off >>= 1) s += __shfl_xor(s, off);
    float mu = s * (1.0f / 128.0f);
    float d0 = x0 - mu, d1 = x1 - mu;
    float ss = d0 * d0 + d1 * d1;
    #pragma unroll
    for (int off = 32; off; off >>= 1) ss += __shfl_xor(ss, off);
    float r = rsqrtf(ss * (1.0f / 128.0f) + 1e-5f);
    float y0 = fmaxf(d0 * r * g[2 * lane]     + b[2 * lane],     0.0f);
    float y1 = fmaxf(d1 * r * g[2 * lane + 1] + b[2 * lane + 1], 0.0f);
    xnext[(size_t)t * 128 + 2 * lane]     = __float2bfloat16(y0);
    xnext[(size_t)t * 128 + 2 * lane + 1] = __float2bfloat16(y1);
}

extern "C" void kernel_launch(void* const* d_in, const int* in_sizes, int n_in,
                              void* d_out, int out_size, void* d_ws, size_t ws_size,
                              hipStream_t stream) {
    const float* x     = (const float*)d_in[0];
    const int*   ei    = (const int*)d_in[1];
    const float* asp   = (const float*)d_in[2];
    const float* actx  = (const float*)d_in[3];
    const float* alat  = (const float*)d_in[4];
    const float* wsp   = (const float*)d_in[5];
    const float* wctx  = (const float*)d_in[6];
    const float* wlat  = (const float*)d_in[7];
    const float* W3    = (const float*)d_in[8];
    const float* Wself = (const float*)d_in[9];
    const float* bias  = (const float*)d_in[10];
    const float* dpow  = (const float*)d_in[11];
    const float* lng   = (const float*)d_in[12];
    const float* lnb   = (const float*)d_in[13];

    const int N = in_sizes[0] / 128;
    const int E = in_sizes[1] / 2;
    const int L = in_sizes[8] / (3 * 128 * 128);
    const int* src = ei;
    const int* tgt = ei + E;

    // workspace carve (256B-aligned)
    char* p = (char*)d_ws;
    auto alloc = [&](size_t bytes) -> void* {
        void* r = (void*)p;
        p += (bytes + 255) & ~(size_t)255;
        return r;
    };
    float* deg    = (float*)alloc((size_t)3 * N * 4);
    float* dinv   = (float*)alloc((size_t)3 * N * 4);
    float* normv  = (float*)alloc((size_t)3 * E * 4);
    int*   cnt    = (int*)  alloc((size_t)N * 4);
    int*   rs     = (int*)  alloc((size_t)(N + 1) * 4);
    int*   nxt    = (int*)  alloc((size_t)N * 4);
    int*   eord   = (int*)  alloc((size_t)E * 4);
    int*   bsum   = (int*)  alloc(1024);
    float* outbuf = (float*)alloc((size_t)N * 128 * 4);
    __hip_bfloat16* Hbuf  = (__hip_bfloat16*)alloc((size_t)N * 384 * 2);
    __hip_bfloat16* xcur  = (__hip_bfloat16*)alloc((size_t)N * 128 * 2); // xb / xnext shared
    __hip_bfloat16* BT    = (__hip_bfloat16*)alloc((size_t)512 * 128 * 2);

    const int nb = cdiv(N, 256);  // scan blocks (<=256 for N<=65536)

    // ---- graph-independent prep: deg, CSR by target, x->bf16 ----
    k_init  <<<cdiv(3 * N, 256), 256, 0, stream>>>(deg, cnt, N);
    k_degcnt<<<cdiv(E, 256),     256, 0, stream>>>(tgt, asp, actx, alat, wsp, wctx, wlat, deg, cnt, N, E);
    k_scan1 <<<nb, 256, 0, stream>>>(cnt, rs, bsum, N);
    k_scan2 <<<1,  256, 0, stream>>>(bsum, nb);
    k_scan3 <<<nb, 256, 0, stream>>>(rs, bsum, N, E);
    k_nextcpy<<<cdiv(N, 256), 256, 0, stream>>>(rs, nxt, N);
    k_scatter<<<cdiv(E, 256), 256, 0, stream>>>(tgt, nxt, eord, E);
    k_x2bf  <<<cdiv(N * 128, 256), 256, 0, stream>>>(x, xcur, N * 128);

    // ---- layers ----
    for (int l = 0; l < L; ++l){
        // last layer computes directly into d_out (fp32 output)
        float* obuf = (l == L - 1) ? (float*)d_out : outbuf;
        k_dinv<<<cdiv(3 * N, 256), 256, 0, stream>>>(deg, dpow + l * 3, dinv, N);
        k_norm<<<cdiv(E, 256), 256, 0, stream>>>(src, tgt, asp, actx, alat, wsp, wctx, wlat,
                                                 dinv, normv, N, E);
        k_wcat<<<256, 256, 0, stream>>>(Wself + (size_t)l * 128 * 128,
                                        W3 + (size_t)l * 3 * 128 * 128, BT);
        dim3 ggrid(cdiv(N, 128), 4);
        k_gemm<<<ggrid, 256, 0, stream>>>(xcur, BT, bias + l * 128, obuf, Hbuf, N);
        k_msg<<<cdiv(N, 4), 256, 0, stream>>>(obuf, Hbuf, normv, src, eord, rs, N);
        if (l < L - 1){
            k_ln<<<cdiv(N, 4), 256, 0, stream>>>(obuf, lng, lnb, xcur, N);
        }
    }
}

// Round 4
// 650.372 us; speedup vs baseline: 1.3261x; 1.3261x over previous
//
#include <hip/hip_runtime.h>
#include <hip/hip_bf16.h>

typedef short bf16x8 __attribute__((ext_vector_type(8)));
typedef float f32x4 __attribute__((ext_vector_type(4)));

static inline int cdiv(int a, int b){ return (a + b - 1) / b; }

// ---------------- init: cnt=0 (N) ----------------
__global__ void k_init(int* __restrict__ cnt, int N){
    int i = blockIdx.x * 256 + threadIdx.x;
    if (i < N) cnt[i] = 0;
}

// ---------------- target count histogram (1 atomic/edge) ----------------
__global__ void k_cnt(const int* __restrict__ tgt, int* __restrict__ cnt, int E){
    int e = blockIdx.x * 256 + threadIdx.x;
    if (e >= E) return;
    atomicAdd(&cnt[tgt[e]], 1);
}

// ---------------- 3-kernel exclusive scan over cnt[N] -> rs ----------------
__global__ void k_scan1(const int* __restrict__ cnt, int* __restrict__ rs,
                        int* __restrict__ bsum, int N){
    __shared__ int s[256];
    int i = blockIdx.x * 256 + threadIdx.x;
    int v = (i < N) ? cnt[i] : 0;
    s[threadIdx.x] = v;
    __syncthreads();
    for (int off = 1; off < 256; off <<= 1){
        int t = (threadIdx.x >= off) ? s[threadIdx.x - off] : 0;
        __syncthreads();
        s[threadIdx.x] += t;
        __syncthreads();
    }
    if (i < N) rs[i] = s[threadIdx.x] - v;      // exclusive
    if (threadIdx.x == 255) bsum[blockIdx.x] = s[255];
}

__global__ void k_scan2(int* __restrict__ bsum, int nb){  // nb <= 256
    __shared__ int s[256];
    int v = (threadIdx.x < nb) ? bsum[threadIdx.x] : 0;
    s[threadIdx.x] = v;
    __syncthreads();
    for (int off = 1; off < 256; off <<= 1){
        int t = (threadIdx.x >= off) ? s[threadIdx.x - off] : 0;
        __syncthreads();
        s[threadIdx.x] += t;
        __syncthreads();
    }
    if (threadIdx.x < nb) bsum[threadIdx.x] = s[threadIdx.x] - v;  // exclusive
}

__global__ void k_scan3(int* __restrict__ rs, const int* __restrict__ bsum,
                        int N, int E){
    int i = blockIdx.x * 256 + threadIdx.x;
    if (i < N) rs[i] += bsum[blockIdx.x];
    if (i == 0) rs[N] = E;
}

__global__ void k_nextcpy(const int* __restrict__ rs, int* __restrict__ nxt, int N){
    int i = blockIdx.x * 256 + threadIdx.x;
    if (i < N) nxt[i] = rs[i];
}

// ---------------- scatter edges into CSR order, carrying src + eff payload ----
__global__ void k_scatter(const int* __restrict__ src, const int* __restrict__ tgt,
                          const float* __restrict__ asp,
                          const float* __restrict__ actx,
                          const float* __restrict__ alat,
                          const float* __restrict__ wsp,
                          const float* __restrict__ wctx,
                          const float* __restrict__ wlat,
                          int* __restrict__ nxt,
                          int* __restrict__ srco, float* __restrict__ effo, int E){
    int e = blockIdx.x * 256 + threadIdx.x;
    if (e >= E) return;
    int t = tgt[e];
    int pos = atomicAdd(&nxt[t], 1);
    srco[pos] = src[e];
    effo[3 * pos + 0] = asp[e]  * wsp[e];
    effo[3 * pos + 1] = actx[e] * wctx[e];
    effo[3 * pos + 2] = alat[e] * wlat[e];
}

// ---------------- deg via coalesced segmented sum; dinv for all layers ----------
__global__ __launch_bounds__(256) void k_deg(
        const float* __restrict__ effo, const int* __restrict__ rs,
        const float* __restrict__ dp,        // deg_power [L*3] fp32
        float* __restrict__ dinv_all,        // [L][N][3]
        int N, int L){
    int w = threadIdx.x >> 6, lane = threadIdx.x & 63;
    int n = blockIdx.x * 4 + w;
    if (n >= N) return;
    int beg = rs[n], end = rs[n + 1];
    float s0 = 0.f, s1 = 0.f, s2 = 0.f;
    for (int i = beg + lane; i < end; i += 64){
        s0 += effo[3 * i + 0];
        s1 += effo[3 * i + 1];
        s2 += effo[3 * i + 2];
    }
    #pragma unroll
    for (int off = 32; off; off >>= 1){
        s0 += __shfl_xor(s0, off);
        s1 += __shfl_xor(s1, off);
        s2 += __shfl_xor(s2, off);
    }
    if (lane == 0){
        float d0 = fmaxf(1.f + s0, 1e-6f);
        float d1 = fmaxf(1.f + s1, 1e-6f);
        float d2 = fmaxf(1.f + s2, 1e-6f);
        for (int l = 0; l < L; ++l){
            size_t base = ((size_t)l * N + n) * 3;
            dinv_all[base + 0] = powf(d0, dp[l * 3 + 0]);
            dinv_all[base + 1] = powf(d1, dp[l * 3 + 1]);
            dinv_all[base + 2] = powf(d2, dp[l * 3 + 2]);
        }
    }
}

// ---------------- x (fp32) -> xb (bf16) ----------------
__global__ void k_x2bf(const float* __restrict__ x, __hip_bfloat16* __restrict__ xb, int n){
    int i = blockIdx.x * 256 + threadIdx.x;
    if (i < n) xb[i] = __float2bfloat16(x[i]);
}

// ---------------- build BT[512][128] = [W_self | W3[0..2]] transposed, fp32->bf16 ----
__global__ void k_wcat(const float* __restrict__ Wself,  // [128,128] (k,j)
                       const float* __restrict__ W3,     // [3,128,128]
                       __hip_bfloat16* __restrict__ BT){ // [512,128] (j,k)
    int i = blockIdx.x * 256 + threadIdx.x;  // 65536
    int j = i >> 7, k = i & 127;
    float v;
    if (j < 128) v = Wself[k * 128 + j];
    else {
        int c = (j >> 7) - 1, jj = j & 127;
        v = W3[(c * 128 + k) * 128 + jj];
    }
    BT[i] = __float2bfloat16(v);
}

// ---------------- GEMM: C[M,512] = A[M,128] @ B[128,512] (B given transposed) ----
// nb==0 cols -> outbuf (fp32, +bias);  nb 1..3 -> Hbuf (bf16, channel nb-1)
__global__ __launch_bounds__(256) void k_gemm(
        const __hip_bfloat16* __restrict__ A,   // [M,128] bf16
        const __hip_bfloat16* __restrict__ BT,  // [512,128] bf16
        const float* __restrict__ bias,         // [128] fp32
        float* __restrict__ outbuf,             // [M,128]
        __hip_bfloat16* __restrict__ Hbuf,      // [M,384]
        int M){
    __shared__ __hip_bfloat16 As[128 * 128];
    __shared__ __hip_bfloat16 Bs[128 * 128];
    const int tid = threadIdx.x;
    const int mb = blockIdx.x, nb = blockIdx.y;
    const int row0 = mb * 128;

    // stage: 16B chunks, XOR-swizzled by (row&15) to kill bank conflicts
    #pragma unroll
    for (int it = 0; it < 8; ++it){
        int v = it * 256 + tid;
        int r = v >> 4, c = v & 15;
        int soff = r * 128 + (((c) ^ (r & 15)) << 3);
        int4 av = {0, 0, 0, 0};
        if (row0 + r < M)
            av = *(const int4*)(A + (size_t)(row0 + r) * 128 + (c << 3));
        *(int4*)(&As[soff]) = av;
        int4 bv = *(const int4*)(BT + (size_t)(nb * 128 + r) * 128 + (c << 3));
        *(int4*)(&Bs[soff]) = bv;
    }
    __syncthreads();

    const int w = tid >> 6, lane = tid & 63;
    const int wm = (w & 1) * 64, wn = (w >> 1) * 64;
    const int lm = lane & 15, lq = lane >> 4;

    f32x4 acc[4][4];
    #pragma unroll
    for (int mt = 0; mt < 4; ++mt)
        #pragma unroll
        for (int nt = 0; nt < 4; ++nt)
            acc[mt][nt] = {0.f, 0.f, 0.f, 0.f};

    #pragma unroll
    for (int kk = 0; kk < 4; ++kk){
        int kc = kk * 4 + lq;  // 16B-chunk index along K
        bf16x8 a[4], b[4];
        #pragma unroll
        for (int mt = 0; mt < 4; ++mt){
            int r = wm + mt * 16 + lm;
            a[mt] = *(const bf16x8*)(&As[r * 128 + ((kc ^ (r & 15)) << 3)]);
        }
        #pragma unroll
        for (int nt = 0; nt < 4; ++nt){
            int r = wn + nt * 16 + lm;
            b[nt] = *(const bf16x8*)(&Bs[r * 128 + ((kc ^ (r & 15)) << 3)]);
        }
        #pragma unroll
        for (int mt = 0; mt < 4; ++mt)
            #pragma unroll
            for (int nt = 0; nt < 4; ++nt)
                acc[mt][nt] = __builtin_amdgcn_mfma_f32_16x16x32_bf16(
                    a[mt], b[nt], acc[mt][nt], 0, 0, 0);
    }

    // epilogue: D[row = (lane>>4)*4 + reg][col = lane&15]
    #pragma unroll
    for (int mt = 0; mt < 4; ++mt){
        #pragma unroll
        for (int nt = 0; nt < 4; ++nt){
            #pragma unroll
            for (int r = 0; r < 4; ++r){
                int row = row0 + wm + mt * 16 + lq * 4 + r;
                int col = wn + nt * 16 + lm;
                if (row < M){
                    float v = acc[mt][nt][r];
                    if (nb == 0)
                        outbuf[(size_t)row * 128 + col] = v + bias[col];
                    else
                        Hbuf[(size_t)row * 384 + (nb - 1) * 128 + col] = __float2bfloat16(v);
                }
            }
        }
    }
}

// ---------------- message passing + optional fused LN/ReLU ----------------
// one wave per target node; norm computed inline from effo/dinv; no atomics
__global__ __launch_bounds__(256) void k_msg(
        float* __restrict__ obuf,                // [N,128] (has self+bias)
        const __hip_bfloat16* __restrict__ Hbuf, // [N,384]
        const float* __restrict__ effo,          // [E,3] CSR order
        const int* __restrict__ srco,            // [E] CSR order
        const int* __restrict__ rs,              // [N+1]
        const float* __restrict__ dinv,          // [N,3] (this layer)
        int N, int doLN,
        const float* __restrict__ g, const float* __restrict__ b,
        __hip_bfloat16* __restrict__ xnext){
    int w = threadIdx.x >> 6, lane = threadIdx.x & 63;
    int t = blockIdx.x * 4 + w;
    if (t >= N) return;
    float dt0 = dinv[3 * t], dt1 = dinv[3 * t + 1], dt2 = dinv[3 * t + 2];
    float* op = obuf + (size_t)t * 128 + lane * 2;
    float accx = op[0], accy = op[1];
    int beg = rs[t], end = rs[t + 1];
    for (int i = beg; i < end; ++i){
        int s = srco[i];
        float n0 = effo[3 * i + 0] * dt0 * dinv[3 * s + 0];
        float n1 = effo[3 * i + 1] * dt1 * dinv[3 * s + 1];
        float n2 = effo[3 * i + 2] * dt2 * dinv[3 * s + 2];
        const __hip_bfloat162* h = (const __hip_bfloat162*)(Hbuf + (size_t)s * 384);
        float2 h0 = __bfloat1622float2(h[lane]);
        float2 h1 = __bfloat1622float2(h[64 + lane]);
        float2 h2 = __bfloat1622float2(h[128 + lane]);
        accx += n0 * h0.x + n1 * h1.x + n2 * h2.x;
        accy += n0 * h0.y + n1 * h1.y + n2 * h2.y;
    }
    if (!doLN){
        op[0] = accx; op[1] = accy;
    } else {
        float s = accx + accy;
        #pragma unroll
        for (int off = 32; off; off >>= 1) s += __shfl_xor(s, off);
        float mu = s * (1.0f / 128.0f);
        float d0 = accx - mu, d1 = accy - mu;
        float ss = d0 * d0 + d1 * d1;
        #pragma unroll
        for (int off = 32; off; off >>= 1) ss += __shfl_xor(ss, off);
        float r = rsqrtf(ss * (1.0f / 128.0f) + 1e-5f);
        float y0 = fmaxf(d0 * r * g[2 * lane]     + b[2 * lane],     0.0f);
        float y1 = fmaxf(d1 * r * g[2 * lane + 1] + b[2 * lane + 1], 0.0f);
        xnext[(size_t)t * 128 + 2 * lane]     = __float2bfloat16(y0);
        xnext[(size_t)t * 128 + 2 * lane + 1] = __float2bfloat16(y1);
    }
}

extern "C" void kernel_launch(void* const* d_in, const int* in_sizes, int n_in,
                              void* d_out, int out_size, void* d_ws, size_t ws_size,
                              hipStream_t stream) {
    const float* x     = (const float*)d_in[0];
    const int*   ei    = (const int*)d_in[1];
    const float* asp   = (const float*)d_in[2];
    const float* actx  = (const float*)d_in[3];
    const float* alat  = (const float*)d_in[4];
    const float* wsp   = (const float*)d_in[5];
    const float* wctx  = (const float*)d_in[6];
    const float* wlat  = (const float*)d_in[7];
    const float* W3    = (const float*)d_in[8];
    const float* Wself = (const float*)d_in[9];
    const float* bias  = (const float*)d_in[10];
    const float* dpow  = (const float*)d_in[11];
    const float* lng   = (const float*)d_in[12];
    const float* lnb   = (const float*)d_in[13];

    const int N = in_sizes[0] / 128;
    const int E = in_sizes[1] / 2;
    const int L = in_sizes[8] / (3 * 128 * 128);
    const int* src = ei;
    const int* tgt = ei + E;

    // workspace carve (256B-aligned)
    char* p = (char*)d_ws;
    auto alloc = [&](size_t bytes) -> void* {
        void* r = (void*)p;
        p += (bytes + 255) & ~(size_t)255;
        return r;
    };
    int*   cnt      = (int*)  alloc((size_t)N * 4);
    int*   rs       = (int*)  alloc((size_t)(N + 1) * 4);
    int*   nxt      = (int*)  alloc((size_t)N * 4);
    int*   bsum     = (int*)  alloc(1024);
    int*   srco     = (int*)  alloc((size_t)E * 4);
    float* effo     = (float*)alloc((size_t)3 * E * 4);
    float* dinv_all = (float*)alloc((size_t)L * N * 3 * 4);
    float* outbuf   = (float*)alloc((size_t)N * 128 * 4);
    __hip_bfloat16* Hbuf = (__hip_bfloat16*)alloc((size_t)N * 384 * 2);
    __hip_bfloat16* xcur = (__hip_bfloat16*)alloc((size_t)N * 128 * 2);
    __hip_bfloat16* BT   = (__hip_bfloat16*)alloc((size_t)512 * 128 * 2);

    const int nb = cdiv(N, 256);  // scan blocks (<=256 for N<=65536)

    // ---- prep: CSR by target (2M atomics total), deg/dinv, x->bf16 ----
    k_init   <<<cdiv(N, 256), 256, 0, stream>>>(cnt, N);
    k_cnt    <<<cdiv(E, 256), 256, 0, stream>>>(tgt, cnt, E);
    k_scan1  <<<nb, 256, 0, stream>>>(cnt, rs, bsum, N);
    k_scan2  <<<1,  256, 0, stream>>>(bsum, nb);
    k_scan3  <<<nb, 256, 0, stream>>>(rs, bsum, N, E);
    k_nextcpy<<<cdiv(N, 256), 256, 0, stream>>>(rs, nxt, N);
    k_scatter<<<cdiv(E, 256), 256, 0, stream>>>(src, tgt, asp, actx, alat, wsp, wctx, wlat,
                                                nxt, srco, effo, E);
    k_deg    <<<cdiv(N, 4), 256, 0, stream>>>(effo, rs, dpow, dinv_all, N, L);
    k_x2bf   <<<cdiv(N * 128, 256), 256, 0, stream>>>(x, xcur, N * 128);

    // ---- layers ----
    for (int l = 0; l < L; ++l){
        float* obuf = (l == L - 1) ? (float*)d_out : outbuf;
        int doLN = (l < L - 1) ? 1 : 0;
        k_wcat<<<256, 256, 0, stream>>>(Wself + (size_t)l * 128 * 128,
                                        W3 + (size_t)l * 3 * 128 * 128, BT);
        dim3 ggrid(cdiv(N, 128), 4);
        k_gemm<<<ggrid, 256, 0, stream>>>(xcur, BT, bias + l * 128, obuf, Hbuf, N);
        k_msg<<<cdiv(N, 4), 256, 0, stream>>>(obuf, Hbuf, effo, srco, rs,
                                              dinv_all + (size_t)l * N * 3,
                                              N, doLN, lng, lnb, xcur);
    }
}

// Round 5
// 604.875 us; speedup vs baseline: 1.4259x; 1.0752x over previous
//
#include <hip/hip_runtime.h>
#include <hip/hip_bf16.h>

typedef short bf16x8 __attribute__((ext_vector_type(8)));
typedef float f32x4 __attribute__((ext_vector_type(4)));

static inline int cdiv(int a, int b){ return (a + b - 1) / b; }

// ---------------- init: cnt=0 (N) ----------------
__global__ void k_init(int* __restrict__ cnt, int N){
    int i = blockIdx.x * 256 + threadIdx.x;
    if (i < N) cnt[i] = 0;
}

// ---------------- target count histogram (1 atomic/edge) ----------------
__global__ void k_cnt(const int* __restrict__ tgt, int* __restrict__ cnt, int E){
    int e = blockIdx.x * 256 + threadIdx.x;
    if (e >= E) return;
    atomicAdd(&cnt[tgt[e]], 1);
}

// ---------------- 3-kernel exclusive scan over cnt[N] -> rs ----------------
__global__ void k_scan1(const int* __restrict__ cnt, int* __restrict__ rs,
                        int* __restrict__ bsum, int N){
    __shared__ int s[256];
    int i = blockIdx.x * 256 + threadIdx.x;
    int v = (i < N) ? cnt[i] : 0;
    s[threadIdx.x] = v;
    __syncthreads();
    for (int off = 1; off < 256; off <<= 1){
        int t = (threadIdx.x >= off) ? s[threadIdx.x - off] : 0;
        __syncthreads();
        s[threadIdx.x] += t;
        __syncthreads();
    }
    if (i < N) rs[i] = s[threadIdx.x] - v;      // exclusive
    if (threadIdx.x == 255) bsum[blockIdx.x] = s[255];
}

__global__ void k_scan2(int* __restrict__ bsum, int nb){  // nb <= 256
    __shared__ int s[256];
    int v = (threadIdx.x < nb) ? bsum[threadIdx.x] : 0;
    s[threadIdx.x] = v;
    __syncthreads();
    for (int off = 1; off < 256; off <<= 1){
        int t = (threadIdx.x >= off) ? s[threadIdx.x - off] : 0;
        __syncthreads();
        s[threadIdx.x] += t;
        __syncthreads();
    }
    if (threadIdx.x < nb) bsum[threadIdx.x] = s[threadIdx.x] - v;  // exclusive
}

__global__ void k_scan3(int* __restrict__ rs, const int* __restrict__ bsum,
                        int N, int E){
    int i = blockIdx.x * 256 + threadIdx.x;
    if (i < N) rs[i] += bsum[blockIdx.x];
    if (i == 0) rs[N] = E;
}

__global__ void k_nextcpy(const int* __restrict__ rs, int* __restrict__ nxt, int N){
    int i = blockIdx.x * 256 + threadIdx.x;
    if (i < N) nxt[i] = rs[i];
}

// ---------------- scatter edges into CSR order: one float4 {eff0,eff1,eff2,src} ----
__global__ void k_scatter(const int* __restrict__ src, const int* __restrict__ tgt,
                          const float* __restrict__ asp,
                          const float* __restrict__ actx,
                          const float* __restrict__ alat,
                          const float* __restrict__ wsp,
                          const float* __restrict__ wctx,
                          const float* __restrict__ wlat,
                          int* __restrict__ nxt,
                          float4* __restrict__ effo4, int E){
    int e = blockIdx.x * 256 + threadIdx.x;
    if (e >= E) return;
    int t = tgt[e];
    int pos = atomicAdd(&nxt[t], 1);
    float4 v;
    v.x = asp[e]  * wsp[e];
    v.y = actx[e] * wctx[e];
    v.z = alat[e] * wlat[e];
    v.w = __int_as_float(src[e]);
    effo4[pos] = v;
}

// ---------------- deg via coalesced segmented sum; dinv for all layers ----------
__global__ __launch_bounds__(256) void k_deg(
        const float4* __restrict__ effo4, const int* __restrict__ rs,
        const float* __restrict__ dp,        // deg_power [L*3] fp32
        float* __restrict__ dinv_all,        // [L][N][3]
        int N, int L){
    int w = threadIdx.x >> 6, lane = threadIdx.x & 63;
    int n = blockIdx.x * 4 + w;
    if (n >= N) return;
    int beg = rs[n], end = rs[n + 1];
    float s0 = 0.f, s1 = 0.f, s2 = 0.f;
    for (int i = beg + lane; i < end; i += 64){
        float4 v = effo4[i];
        s0 += v.x; s1 += v.y; s2 += v.z;
    }
    #pragma unroll
    for (int off = 32; off; off >>= 1){
        s0 += __shfl_xor(s0, off);
        s1 += __shfl_xor(s1, off);
        s2 += __shfl_xor(s2, off);
    }
    if (lane == 0){
        float d0 = fmaxf(1.f + s0, 1e-6f);
        float d1 = fmaxf(1.f + s1, 1e-6f);
        float d2 = fmaxf(1.f + s2, 1e-6f);
        for (int l = 0; l < L; ++l){
            size_t base = ((size_t)l * N + n) * 3;
            dinv_all[base + 0] = powf(d0, dp[l * 3 + 0]);
            dinv_all[base + 1] = powf(d1, dp[l * 3 + 1]);
            dinv_all[base + 2] = powf(d2, dp[l * 3 + 2]);
        }
    }
}

// ---------------- per-layer: nv[e] = {eff_c * dinv_c[src], src_bits} ----------
__global__ void k_normv(const float4* __restrict__ effo4,
                        const float* __restrict__ dinv,  // this layer [N][3]
                        float4* __restrict__ nv, int E){
    int e = blockIdx.x * 256 + threadIdx.x;
    if (e >= E) return;
    float4 v = effo4[e];
    int s = __float_as_int(v.w);
    float4 o;
    o.x = v.x * dinv[3 * s + 0];
    o.y = v.y * dinv[3 * s + 1];
    o.z = v.z * dinv[3 * s + 2];
    o.w = v.w;
    nv[e] = o;
}

// ---------------- x (fp32) -> xb (bf16) ----------------
__global__ void k_x2bf(const float* __restrict__ x, __hip_bfloat16* __restrict__ xb, int n){
    int i = blockIdx.x * 256 + threadIdx.x;
    if (i < n) xb[i] = __float2bfloat16(x[i]);
}

// ---------------- build BT[512][128] = [W_self | W3[0..2]] transposed, fp32->bf16 ----
__global__ void k_wcat(const float* __restrict__ Wself,  // [128,128] (k,j)
                       const float* __restrict__ W3,     // [3,128,128]
                       __hip_bfloat16* __restrict__ BT){ // [512,128] (j,k)
    int i = blockIdx.x * 256 + threadIdx.x;  // 65536
    int j = i >> 7, k = i & 127;
    float v;
    if (j < 128) v = Wself[k * 128 + j];
    else {
        int c = (j >> 7) - 1, jj = j & 127;
        v = W3[(c * 128 + k) * 128 + jj];
    }
    BT[i] = __float2bfloat16(v);
}

// ---------------- GEMM: C[M,512] = A[M,128] @ B[128,512] (B given transposed) ----
// nb==0 cols -> outbuf (fp32, +bias);  nb 1..3 -> Hbuf (bf16, channel nb-1)
__global__ __launch_bounds__(256) void k_gemm(
        const __hip_bfloat16* __restrict__ A,   // [M,128] bf16
        const __hip_bfloat16* __restrict__ BT,  // [512,128] bf16
        const float* __restrict__ bias,         // [128] fp32
        float* __restrict__ outbuf,             // [M,128]
        __hip_bfloat16* __restrict__ Hbuf,      // [M,384]
        int M){
    __shared__ __hip_bfloat16 As[128 * 128];
    __shared__ __hip_bfloat16 Bs[128 * 128];
    const int tid = threadIdx.x;
    const int mb = blockIdx.x, nb = blockIdx.y;
    const int row0 = mb * 128;

    // stage: 16B chunks, XOR-swizzled by (row&15) to kill bank conflicts
    #pragma unroll
    for (int it = 0; it < 8; ++it){
        int v = it * 256 + tid;
        int r = v >> 4, c = v & 15;
        int soff = r * 128 + (((c) ^ (r & 15)) << 3);
        int4 av = {0, 0, 0, 0};
        if (row0 + r < M)
            av = *(const int4*)(A + (size_t)(row0 + r) * 128 + (c << 3));
        *(int4*)(&As[soff]) = av;
        int4 bv = *(const int4*)(BT + (size_t)(nb * 128 + r) * 128 + (c << 3));
        *(int4*)(&Bs[soff]) = bv;
    }
    __syncthreads();

    const int w = tid >> 6, lane = tid & 63;
    const int wm = (w & 1) * 64, wn = (w >> 1) * 64;
    const int lm = lane & 15, lq = lane >> 4;

    f32x4 acc[4][4];
    #pragma unroll
    for (int mt = 0; mt < 4; ++mt)
        #pragma unroll
        for (int nt = 0; nt < 4; ++nt)
            acc[mt][nt] = {0.f, 0.f, 0.f, 0.f};

    #pragma unroll
    for (int kk = 0; kk < 4; ++kk){
        int kc = kk * 4 + lq;  // 16B-chunk index along K
        bf16x8 a[4], b[4];
        #pragma unroll
        for (int mt = 0; mt < 4; ++mt){
            int r = wm + mt * 16 + lm;
            a[mt] = *(const bf16x8*)(&As[r * 128 + ((kc ^ (r & 15)) << 3)]);
        }
        #pragma unroll
        for (int nt = 0; nt < 4; ++nt){
            int r = wn + nt * 16 + lm;
            b[nt] = *(const bf16x8*)(&Bs[r * 128 + ((kc ^ (r & 15)) << 3)]);
        }
        #pragma unroll
        for (int mt = 0; mt < 4; ++mt)
            #pragma unroll
            for (int nt = 0; nt < 4; ++nt)
                acc[mt][nt] = __builtin_amdgcn_mfma_f32_16x16x32_bf16(
                    a[mt], b[nt], acc[mt][nt], 0, 0, 0);
    }

    // epilogue: D[row = (lane>>4)*4 + reg][col = lane&15]
    #pragma unroll
    for (int mt = 0; mt < 4; ++mt){
        #pragma unroll
        for (int nt = 0; nt < 4; ++nt){
            #pragma unroll
            for (int r = 0; r < 4; ++r){
                int row = row0 + wm + mt * 16 + lq * 4 + r;
                int col = wn + nt * 16 + lm;
                if (row < M){
                    float v = acc[mt][nt][r];
                    if (nb == 0)
                        outbuf[(size_t)row * 128 + col] = v + bias[col];
                    else
                        Hbuf[(size_t)row * 384 + (nb - 1) * 128 + col] = __float2bfloat16(v);
                }
            }
        }
    }
}

// ---------------- message passing + optional fused LN/ReLU ----------------
// one wave per target; per-edge: 1 uniform dwordx4 + 3 gathers; unroll x2;
// channel-separate accumulators, target dinv applied once at the end
__global__ __launch_bounds__(256) void k_msg(
        float* __restrict__ obuf,                // [N,128] (has self+bias)
        const __hip_bfloat16* __restrict__ Hbuf, // [N,384]
        const float4* __restrict__ nv,           // [E] {n0,n1,n2,src_bits}
        const int* __restrict__ rs,              // [N+1]
        const float* __restrict__ dinv,          // [N,3] (this layer)
        int N, int doLN,
        const float* __restrict__ g, const float* __restrict__ b,
        __hip_bfloat16* __restrict__ xnext){
    int w = threadIdx.x >> 6, lane = threadIdx.x & 63;
    int t = blockIdx.x * 4 + w;
    if (t >= N) return;
    float dt0 = dinv[3 * t], dt1 = dinv[3 * t + 1], dt2 = dinv[3 * t + 2];
    float ax0 = 0.f, ay0 = 0.f, ax1 = 0.f, ay1 = 0.f, ax2 = 0.f, ay2 = 0.f;
    int beg = rs[t], end = rs[t + 1];
    int i = beg;
    for (; i + 2 <= end; i += 2){
        float4 nA = nv[i], nB = nv[i + 1];
        const __hip_bfloat162* hA =
            (const __hip_bfloat162*)(Hbuf + (size_t)__float_as_int(nA.w) * 384);
        const __hip_bfloat162* hB =
            (const __hip_bfloat162*)(Hbuf + (size_t)__float_as_int(nB.w) * 384);
        __hip_bfloat162 a0 = hA[lane], a1 = hA[64 + lane], a2 = hA[128 + lane];
        __hip_bfloat162 b0 = hB[lane], b1 = hB[64 + lane], b2 = hB[128 + lane];
        float2 fa0 = __bfloat1622float2(a0);
        float2 fa1 = __bfloat1622float2(a1);
        float2 fa2 = __bfloat1622float2(a2);
        float2 fb0 = __bfloat1622float2(b0);
        float2 fb1 = __bfloat1622float2(b1);
        float2 fb2 = __bfloat1622float2(b2);
        ax0 += nA.x * fa0.x; ay0 += nA.x * fa0.y;
        ax1 += nA.y * fa1.x; ay1 += nA.y * fa1.y;
        ax2 += nA.z * fa2.x; ay2 += nA.z * fa2.y;
        ax0 += nB.x * fb0.x; ay0 += nB.x * fb0.y;
        ax1 += nB.y * fb1.x; ay1 += nB.y * fb1.y;
        ax2 += nB.z * fb2.x; ay2 += nB.z * fb2.y;
    }
    if (i < end){
        float4 nA = nv[i];
        const __hip_bfloat162* hA =
            (const __hip_bfloat162*)(Hbuf + (size_t)__float_as_int(nA.w) * 384);
        float2 fa0 = __bfloat1622float2(hA[lane]);
        float2 fa1 = __bfloat1622float2(hA[64 + lane]);
        float2 fa2 = __bfloat1622float2(hA[128 + lane]);
        ax0 += nA.x * fa0.x; ay0 += nA.x * fa0.y;
        ax1 += nA.y * fa1.x; ay1 += nA.y * fa1.y;
        ax2 += nA.z * fa2.x; ay2 += nA.z * fa2.y;
    }
    float* op = obuf + (size_t)t * 128 + lane * 2;
    float rx = op[0] + dt0 * ax0 + dt1 * ax1 + dt2 * ax2;
    float ry = op[1] + dt0 * ay0 + dt1 * ay1 + dt2 * ay2;
    if (!doLN){
        op[0] = rx; op[1] = ry;
    } else {
        float s = rx + ry;
        #pragma unroll
        for (int off = 32; off; off >>= 1) s += __shfl_xor(s, off);
        float mu = s * (1.0f / 128.0f);
        float d0 = rx - mu, d1 = ry - mu;
        float ss = d0 * d0 + d1 * d1;
        #pragma unroll
        for (int off = 32; off; off >>= 1) ss += __shfl_xor(ss, off);
        float r = rsqrtf(ss * (1.0f / 128.0f) + 1e-5f);
        float y0 = fmaxf(d0 * r * g[2 * lane]     + b[2 * lane],     0.0f);
        float y1 = fmaxf(d1 * r * g[2 * lane + 1] + b[2 * lane + 1], 0.0f);
        xnext[(size_t)t * 128 + 2 * lane]     = __float2bfloat16(y0);
        xnext[(size_t)t * 128 + 2 * lane + 1] = __float2bfloat16(y1);
    }
}

extern "C" void kernel_launch(void* const* d_in, const int* in_sizes, int n_in,
                              void* d_out, int out_size, void* d_ws, size_t ws_size,
                              hipStream_t stream) {
    const float* x     = (const float*)d_in[0];
    const int*   ei    = (const int*)d_in[1];
    const float* asp   = (const float*)d_in[2];
    const float* actx  = (const float*)d_in[3];
    const float* alat  = (const float*)d_in[4];
    const float* wsp   = (const float*)d_in[5];
    const float* wctx  = (const float*)d_in[6];
    const float* wlat  = (const float*)d_in[7];
    const float* W3    = (const float*)d_in[8];
    const float* Wself = (const float*)d_in[9];
    const float* bias  = (const float*)d_in[10];
    const float* dpow  = (const float*)d_in[11];
    const float* lng   = (const float*)d_in[12];
    const float* lnb   = (const float*)d_in[13];

    const int N = in_sizes[0] / 128;
    const int E = in_sizes[1] / 2;
    const int L = in_sizes[8] / (3 * 128 * 128);
    const int* src = ei;
    const int* tgt = ei + E;

    // workspace carve (256B-aligned)
    char* p = (char*)d_ws;
    auto alloc = [&](size_t bytes) -> void* {
        void* r = (void*)p;
        p += (bytes + 255) & ~(size_t)255;
        return r;
    };
    int*    cnt      = (int*)   alloc((size_t)N * 4);
    int*    rs       = (int*)   alloc((size_t)(N + 1) * 4);
    int*    nxt      = (int*)   alloc((size_t)N * 4);
    int*    bsum     = (int*)   alloc(1024);
    float4* effo4    = (float4*)alloc((size_t)E * 16);
    float4* nv       = (float4*)alloc((size_t)E * 16);
    float*  dinv_all = (float*) alloc((size_t)L * N * 3 * 4);
    float*  outbuf   = (float*) alloc((size_t)N * 128 * 4);
    __hip_bfloat16* Hbuf = (__hip_bfloat16*)alloc((size_t)N * 384 * 2);
    __hip_bfloat16* xcur = (__hip_bfloat16*)alloc((size_t)N * 128 * 2);
    __hip_bfloat16* BT   = (__hip_bfloat16*)alloc((size_t)512 * 128 * 2);

    const int nb = cdiv(N, 256);  // scan blocks (<=256 for N<=65536)

    // ---- prep: CSR by target (2M atomics total), deg/dinv, x->bf16 ----
    k_init   <<<cdiv(N, 256), 256, 0, stream>>>(cnt, N);
    k_cnt    <<<cdiv(E, 256), 256, 0, stream>>>(tgt, cnt, E);
    k_scan1  <<<nb, 256, 0, stream>>>(cnt, rs, bsum, N);
    k_scan2  <<<1,  256, 0, stream>>>(bsum, nb);
    k_scan3  <<<nb, 256, 0, stream>>>(rs, bsum, N, E);
    k_nextcpy<<<cdiv(N, 256), 256, 0, stream>>>(rs, nxt, N);
    k_scatter<<<cdiv(E, 256), 256, 0, stream>>>(src, tgt, asp, actx, alat, wsp, wctx, wlat,
                                                nxt, effo4, E);
    k_deg    <<<cdiv(N, 4), 256, 0, stream>>>(effo4, rs, dpow, dinv_all, N, L);
    k_x2bf   <<<cdiv(N * 128, 256), 256, 0, stream>>>(x, xcur, N * 128);

    // ---- layers ----
    for (int l = 0; l < L; ++l){
        float* obuf = (l == L - 1) ? (float*)d_out : outbuf;
        int doLN = (l < L - 1) ? 1 : 0;
        const float* dinv_l = dinv_all + (size_t)l * N * 3;
        k_normv<<<cdiv(E, 256), 256, 0, stream>>>(effo4, dinv_l, nv, E);
        k_wcat<<<256, 256, 0, stream>>>(Wself + (size_t)l * 128 * 128,
                                        W3 + (size_t)l * 3 * 128 * 128, BT);
        dim3 ggrid(cdiv(N, 128), 4);
        k_gemm<<<ggrid, 256, 0, stream>>>(xcur, BT, bias + l * 128, obuf, Hbuf, N);
        k_msg<<<cdiv(N, 4), 256, 0, stream>>>(obuf, Hbuf, nv, rs, dinv_l,
                                              N, doLN, lng, lnb, xcur);
    }
}

// Round 6
// 492.857 us; speedup vs baseline: 1.7500x; 1.2273x over previous
//
#include <hip/hip_runtime.h>
#include <hip/hip_bf16.h>

typedef short bf16x8 __attribute__((ext_vector_type(8)));
typedef float f32x4 __attribute__((ext_vector_type(4)));

static inline int cdiv(int a, int b){ return (a + b - 1) / b; }

// ---------------- init: cnt=0 (N) ----------------
__global__ void k_init(int* __restrict__ cnt, int N){
    int i = blockIdx.x * 256 + threadIdx.x;
    if (i < N) cnt[i] = 0;
}

// ---------------- target count histogram (1 atomic/edge) ----------------
__global__ void k_cnt(const int* __restrict__ tgt, int* __restrict__ cnt, int E){
    int e = blockIdx.x * 256 + threadIdx.x;
    if (e >= E) return;
    atomicAdd(&cnt[tgt[e]], 1);
}

// ---------------- 3-kernel exclusive scan over cnt[N] -> rs ----------------
__global__ void k_scan1(const int* __restrict__ cnt, int* __restrict__ rs,
                        int* __restrict__ bsum, int N){
    __shared__ int s[256];
    int i = blockIdx.x * 256 + threadIdx.x;
    int v = (i < N) ? cnt[i] : 0;
    s[threadIdx.x] = v;
    __syncthreads();
    for (int off = 1; off < 256; off <<= 1){
        int t = (threadIdx.x >= off) ? s[threadIdx.x - off] : 0;
        __syncthreads();
        s[threadIdx.x] += t;
        __syncthreads();
    }
    if (i < N) rs[i] = s[threadIdx.x] - v;      // exclusive
    if (threadIdx.x == 255) bsum[blockIdx.x] = s[255];
}

__global__ void k_scan2(int* __restrict__ bsum, int nb){  // nb <= 256
    __shared__ int s[256];
    int v = (threadIdx.x < nb) ? bsum[threadIdx.x] : 0;
    s[threadIdx.x] = v;
    __syncthreads();
    for (int off = 1; off < 256; off <<= 1){
        int t = (threadIdx.x >= off) ? s[threadIdx.x - off] : 0;
        __syncthreads();
        s[threadIdx.x] += t;
        __syncthreads();
    }
    if (threadIdx.x < nb) bsum[threadIdx.x] = s[threadIdx.x] - v;  // exclusive
}

__global__ void k_scan3(int* __restrict__ rs, const int* __restrict__ bsum,
                        int N, int E){
    int i = blockIdx.x * 256 + threadIdx.x;
    if (i < N) rs[i] += bsum[blockIdx.x];
    if (i == 0) rs[N] = E;
}

__global__ void k_nextcpy(const int* __restrict__ rs, int* __restrict__ nxt, int N){
    int i = blockIdx.x * 256 + threadIdx.x;
    if (i < N) nxt[i] = rs[i];
}

// ---------------- scatter edges into CSR order: one float4 {eff0,eff1,eff2,src} ----
__global__ void k_scatter(const int* __restrict__ src, const int* __restrict__ tgt,
                          const float* __restrict__ asp,
                          const float* __restrict__ actx,
                          const float* __restrict__ alat,
                          const float* __restrict__ wsp,
                          const float* __restrict__ wctx,
                          const float* __restrict__ wlat,
                          int* __restrict__ nxt,
                          float4* __restrict__ effo4, int E){
    int e = blockIdx.x * 256 + threadIdx.x;
    if (e >= E) return;
    int t = tgt[e];
    int pos = atomicAdd(&nxt[t], 1);
    float4 v;
    v.x = asp[e]  * wsp[e];
    v.y = actx[e] * wctx[e];
    v.z = alat[e] * wlat[e];
    v.w = __int_as_float(src[e]);
    effo4[pos] = v;
}

// ---------------- deg via coalesced segmented sum; dinv for all layers ----------
__global__ __launch_bounds__(256) void k_deg(
        const float4* __restrict__ effo4, const int* __restrict__ rs,
        const float* __restrict__ dp,        // deg_power [L*3] fp32
        float* __restrict__ dinv_all,        // [L][N][3]
        int N, int L){
    int w = threadIdx.x >> 6, lane = threadIdx.x & 63;
    int n = blockIdx.x * 4 + w;
    if (n >= N) return;
    int beg = rs[n], end = rs[n + 1];
    float s0 = 0.f, s1 = 0.f, s2 = 0.f;
    for (int i = beg + lane; i < end; i += 64){
        float4 v = effo4[i];
        s0 += v.x; s1 += v.y; s2 += v.z;
    }
    #pragma unroll
    for (int off = 32; off; off >>= 1){
        s0 += __shfl_xor(s0, off);
        s1 += __shfl_xor(s1, off);
        s2 += __shfl_xor(s2, off);
    }
    if (lane == 0){
        float d0 = fmaxf(1.f + s0, 1e-6f);
        float d1 = fmaxf(1.f + s1, 1e-6f);
        float d2 = fmaxf(1.f + s2, 1e-6f);
        for (int l = 0; l < L; ++l){
            size_t base = ((size_t)l * N + n) * 3;
            dinv_all[base + 0] = powf(d0, dp[l * 3 + 0]);
            dinv_all[base + 1] = powf(d1, dp[l * 3 + 1]);
            dinv_all[base + 2] = powf(d2, dp[l * 3 + 2]);
        }
    }
}

// ---------------- per-layer: nv[e] = {eff_c * dinv_c[src], src_bits} ----------
__global__ void k_normv(const float4* __restrict__ effo4,
                        const float* __restrict__ dinv,  // this layer [N][3]
                        float4* __restrict__ nv, int E){
    int e = blockIdx.x * 256 + threadIdx.x;
    if (e >= E) return;
    float4 v = effo4[e];
    int s = __float_as_int(v.w);
    float4 o;
    o.x = v.x * dinv[3 * s + 0];
    o.y = v.y * dinv[3 * s + 1];
    o.z = v.z * dinv[3 * s + 2];
    o.w = v.w;
    nv[e] = o;
}

// ---------------- x (fp32) -> A'[:,0:128] (bf16, row stride 512) ----------------
__global__ void k_x2bf(const float* __restrict__ x, __hip_bfloat16* __restrict__ Ap, int n){
    int i = blockIdx.x * 256 + threadIdx.x;
    if (i < n) Ap[(size_t)(i >> 7) * 512 + (i & 127)] = __float2bfloat16(x[i]);
}

// ---------------- build BT[128][512]: B[k,j] = [W_self; W3[0..2]][k][j] ----------
__global__ void k_wcat(const float* __restrict__ Wself,  // [128,128] (k,j)
                       const float* __restrict__ W3,     // [3,128,128]
                       __hip_bfloat16* __restrict__ BT){ // [j][k] = [128][512]
    int i = blockIdx.x * 256 + threadIdx.x;  // 65536
    int j = i >> 9, k = i & 511;
    float v;
    if (k < 128) v = Wself[k * 128 + j];
    else {
        int c = (k >> 7) - 1, kk = k & 127;
        v = W3[(c * 128 + kk) * 128 + j];
    }
    BT[i] = __float2bfloat16(v);
}

// ---------------- aggregate: Y_c[t] = dt_c * sum_e nv_c[e] * x[src[e]] ----------
// one gathered 4B load/lane/edge (vs 3 before); unroll x4 for MLP
__global__ __launch_bounds__(256) void k_msg(
        __hip_bfloat16* __restrict__ Ap,   // [N,512]: cols 0..127 = x (read), 128..511 = Y (write)
        const float4* __restrict__ nv,     // [E] {n0,n1,n2,src_bits} CSR order
        const int* __restrict__ rs,        // [N+1]
        const float* __restrict__ dinv,    // [N,3] (this layer)
        int N){
    int w = threadIdx.x >> 6, lane = threadIdx.x & 63;
    int t = blockIdx.x * 4 + w;
    if (t >= N) return;
    float ax0 = 0.f, ay0 = 0.f, ax1 = 0.f, ay1 = 0.f, ax2 = 0.f, ay2 = 0.f;
    int beg = rs[t], end = rs[t + 1];
    int i = beg;
    for (; i + 4 <= end; i += 4){
        float4 n0 = nv[i], n1 = nv[i + 1], n2 = nv[i + 2], n3 = nv[i + 3];
        const __hip_bfloat162* p0 = (const __hip_bfloat162*)(Ap + (size_t)__float_as_int(n0.w) * 512);
        const __hip_bfloat162* p1 = (const __hip_bfloat162*)(Ap + (size_t)__float_as_int(n1.w) * 512);
        const __hip_bfloat162* p2 = (const __hip_bfloat162*)(Ap + (size_t)__float_as_int(n2.w) * 512);
        const __hip_bfloat162* p3 = (const __hip_bfloat162*)(Ap + (size_t)__float_as_int(n3.w) * 512);
        __hip_bfloat162 v0 = p0[lane], v1 = p1[lane], v2 = p2[lane], v3 = p3[lane];
        float2 f0 = __bfloat1622float2(v0);
        float2 f1 = __bfloat1622float2(v1);
        float2 f2 = __bfloat1622float2(v2);
        float2 f3 = __bfloat1622float2(v3);
        ax0 += n0.x * f0.x; ay0 += n0.x * f0.y;
        ax1 += n0.y * f0.x; ay1 += n0.y * f0.y;
        ax2 += n0.z * f0.x; ay2 += n0.z * f0.y;
        ax0 += n1.x * f1.x; ay0 += n1.x * f1.y;
        ax1 += n1.y * f1.x; ay1 += n1.y * f1.y;
        ax2 += n1.z * f1.x; ay2 += n1.z * f1.y;
        ax0 += n2.x * f2.x; ay0 += n2.x * f2.y;
        ax1 += n2.y * f2.x; ay1 += n2.y * f2.y;
        ax2 += n2.z * f2.x; ay2 += n2.z * f2.y;
        ax0 += n3.x * f3.x; ay0 += n3.x * f3.y;
        ax1 += n3.y * f3.x; ay1 += n3.y * f3.y;
        ax2 += n3.z * f3.x; ay2 += n3.z * f3.y;
    }
    for (; i < end; ++i){
        float4 n0 = nv[i];
        const __hip_bfloat162* p0 = (const __hip_bfloat162*)(Ap + (size_t)__float_as_int(n0.w) * 512);
        float2 f0 = __bfloat1622float2(p0[lane]);
        ax0 += n0.x * f0.x; ay0 += n0.x * f0.y;
        ax1 += n0.y * f0.x; ay1 += n0.y * f0.y;
        ax2 += n0.z * f0.x; ay2 += n0.z * f0.y;
    }
    float dt0 = dinv[3 * t], dt1 = dinv[3 * t + 1], dt2 = dinv[3 * t + 2];
    __hip_bfloat162* yo = (__hip_bfloat162*)(Ap + (size_t)t * 512 + 128) + lane;
    float2 r0 = {dt0 * ax0, dt0 * ay0};
    float2 r1 = {dt1 * ax1, dt1 * ay1};
    float2 r2 = {dt2 * ax2, dt2 * ay2};
    yo[0]   = __float22bfloat162_rn(r0);
    yo[64]  = __float22bfloat162_rn(r1);
    yo[128] = __float22bfloat162_rn(r2);
}

// ---------------- GEMM: out[M,128] = A'[M,512] @ B[512,128] + bias ----------
__global__ __launch_bounds__(256) void k_gemm(
        const __hip_bfloat16* __restrict__ A,   // [M,512] bf16
        const __hip_bfloat16* __restrict__ BT,  // [128,512] bf16 ([j][k])
        const float* __restrict__ bias,         // [128] fp32
        float* __restrict__ outbuf,             // [M,128]
        int M){
    __shared__ __hip_bfloat16 As[128 * 128];
    __shared__ __hip_bfloat16 Bs[128 * 128];
    const int tid = threadIdx.x;
    const int row0 = blockIdx.x * 128;
    const int w = tid >> 6, lane = tid & 63;
    const int wm = (w & 1) * 64, wn = (w >> 1) * 64;
    const int lm = lane & 15, lq = lane >> 4;

    f32x4 acc[4][4];
    #pragma unroll
    for (int mt = 0; mt < 4; ++mt)
        #pragma unroll
        for (int nt = 0; nt < 4; ++nt)
            acc[mt][nt] = {0.f, 0.f, 0.f, 0.f};

    for (int kt = 0; kt < 4; ++kt){
        // stage K-tile: 16B chunks, XOR-swizzled by (row&15)
        #pragma unroll
        for (int it = 0; it < 8; ++it){
            int v = it * 256 + tid;
            int r = v >> 4, c = v & 15;
            int soff = r * 128 + ((c ^ (r & 15)) << 3);
            int4 av = {0, 0, 0, 0};
            if (row0 + r < M)
                av = *(const int4*)(A + (size_t)(row0 + r) * 512 + kt * 128 + (c << 3));
            *(int4*)(&As[soff]) = av;
            int4 bv = *(const int4*)(BT + (size_t)r * 512 + kt * 128 + (c << 3));
            *(int4*)(&Bs[soff]) = bv;
        }
        __syncthreads();

        #pragma unroll
        for (int kk = 0; kk < 4; ++kk){
            int kc = kk * 4 + lq;  // 16B-chunk index along local K
            bf16x8 a[4], b[4];
            #pragma unroll
            for (int mt = 0; mt < 4; ++mt){
                int r = wm + mt * 16 + lm;
                a[mt] = *(const bf16x8*)(&As[r * 128 + ((kc ^ (r & 15)) << 3)]);
            }
            #pragma unroll
            for (int nt = 0; nt < 4; ++nt){
                int r = wn + nt * 16 + lm;
                b[nt] = *(const bf16x8*)(&Bs[r * 128 + ((kc ^ (r & 15)) << 3)]);
            }
            #pragma unroll
            for (int mt = 0; mt < 4; ++mt)
                #pragma unroll
                for (int nt = 0; nt < 4; ++nt)
                    acc[mt][nt] = __builtin_amdgcn_mfma_f32_16x16x32_bf16(
                        a[mt], b[nt], acc[mt][nt], 0, 0, 0);
        }
        __syncthreads();
    }

    // epilogue: D[row = lq*4 + reg][col = lm] per 16x16 fragment
    #pragma unroll
    for (int mt = 0; mt < 4; ++mt){
        #pragma unroll
        for (int nt = 0; nt < 4; ++nt){
            int col = wn + nt * 16 + lm;
            #pragma unroll
            for (int r = 0; r < 4; ++r){
                int row = row0 + wm + mt * 16 + lq * 4 + r;
                if (row < M)
                    outbuf[(size_t)row * 128 + col] = acc[mt][nt][r] + bias[col];
            }
        }
    }
}

// ---------------- LayerNorm + ReLU -> bf16 into A'[:,0:128] ----------------
__global__ __launch_bounds__(256) void k_ln(
        const float* __restrict__ outbuf,
        const float* __restrict__ g,
        const float* __restrict__ b,
        __hip_bfloat16* __restrict__ Ap, int N){
    int w = threadIdx.x >> 6, lane = threadIdx.x & 63;
    int t = blockIdx.x * 4 + w;
    if (t >= N) return;
    const float* row = outbuf + (size_t)t * 128;
    float x0 = row[2 * lane], x1 = row[2 * lane + 1];
    float s = x0 + x1;
    #pragma unroll
    for (int off = 32; off; off >>= 1) s += __shfl_xor(s, off);
    float mu = s * (1.0f / 128.0f);
    float d0 = x0 - mu, d1 = x1 - mu;
    float ss = d0 * d0 + d1 * d1;
    #pragma unroll
    for (int off = 32; off; off >>= 1) ss += __shfl_xor(ss, off);
    float r = rsqrtf(ss * (1.0f / 128.0f) + 1e-5f);
    float y0 = fmaxf(d0 * r * g[2 * lane]     + b[2 * lane],     0.0f);
    float y1 = fmaxf(d1 * r * g[2 * lane + 1] + b[2 * lane + 1], 0.0f);
    float2 y = {y0, y1};
    *((__hip_bfloat162*)(Ap + (size_t)t * 512) + lane) = __float22bfloat162_rn(y);
}

extern "C" void kernel_launch(void* const* d_in, const int* in_sizes, int n_in,
                              void* d_out, int out_size, void* d_ws, size_t ws_size,
                              hipStream_t stream) {
    const float* x     = (const float*)d_in[0];
    const int*   ei    = (const int*)d_in[1];
    const float* asp   = (const float*)d_in[2];
    const float* actx  = (const float*)d_in[3];
    const float* alat  = (const float*)d_in[4];
    const float* wsp   = (const float*)d_in[5];
    const float* wctx  = (const float*)d_in[6];
    const float* wlat  = (const float*)d_in[7];
    const float* W3    = (const float*)d_in[8];
    const float* Wself = (const float*)d_in[9];
    const float* bias  = (const float*)d_in[10];
    const float* dpow  = (const float*)d_in[11];
    const float* lng   = (const float*)d_in[12];
    const float* lnb   = (const float*)d_in[13];

    const int N = in_sizes[0] / 128;
    const int E = in_sizes[1] / 2;
    const int L = in_sizes[8] / (3 * 128 * 128);
    const int* src = ei;
    const int* tgt = ei + E;

    // workspace carve (256B-aligned)
    char* p = (char*)d_ws;
    auto alloc = [&](size_t bytes) -> void* {
        void* r = (void*)p;
        p += (bytes + 255) & ~(size_t)255;
        return r;
    };
    int*    cnt      = (int*)   alloc((size_t)N * 4);
    int*    rs       = (int*)   alloc((size_t)(N + 1) * 4);
    int*    nxt      = (int*)   alloc((size_t)N * 4);
    int*    bsum     = (int*)   alloc(1024);
    float4* effo4    = (float4*)alloc((size_t)E * 16);
    float4* nv       = (float4*)alloc((size_t)E * 16);
    float*  dinv_all = (float*) alloc((size_t)L * N * 3 * 4);
    float*  outbuf   = (float*) alloc((size_t)N * 128 * 4);
    __hip_bfloat16* Ap = (__hip_bfloat16*)alloc((size_t)N * 512 * 2);  // [x|Y0|Y1|Y2]
    __hip_bfloat16* BT = (__hip_bfloat16*)alloc((size_t)128 * 512 * 2);

    const int nb = cdiv(N, 256);  // scan blocks (<=256 for N<=65536)

    // ---- prep: CSR by target (2M atomics total), deg/dinv, x->A' ----
    k_init   <<<cdiv(N, 256), 256, 0, stream>>>(cnt, N);
    k_cnt    <<<cdiv(E, 256), 256, 0, stream>>>(tgt, cnt, E);
    k_scan1  <<<nb, 256, 0, stream>>>(cnt, rs, bsum, N);
    k_scan2  <<<1,  256, 0, stream>>>(bsum, nb);
    k_scan3  <<<nb, 256, 0, stream>>>(rs, bsum, N, E);
    k_nextcpy<<<cdiv(N, 256), 256, 0, stream>>>(rs, nxt, N);
    k_scatter<<<cdiv(E, 256), 256, 0, stream>>>(src, tgt, asp, actx, alat, wsp, wctx, wlat,
                                                nxt, effo4, E);
    k_deg    <<<cdiv(N, 4), 256, 0, stream>>>(effo4, rs, dpow, dinv_all, N, L);
    k_x2bf   <<<cdiv(N * 128, 256), 256, 0, stream>>>(x, Ap, N * 128);

    // ---- layers ----
    for (int l = 0; l < L; ++l){
        float* obuf = (l == L - 1) ? (float*)d_out : outbuf;
        const float* dinv_l = dinv_all + (size_t)l * N * 3;
        k_normv<<<cdiv(E, 256), 256, 0, stream>>>(effo4, dinv_l, nv, E);
        k_msg  <<<cdiv(N, 4), 256, 0, stream>>>(Ap, nv, rs, dinv_l, N);
        k_wcat <<<256, 256, 0, stream>>>(Wself + (size_t)l * 128 * 128,
                                         W3 + (size_t)l * 3 * 128 * 128, BT);
        k_gemm <<<cdiv(N, 128), 256, 0, stream>>>(Ap, BT, bias + l * 128, obuf, N);
        if (l < L - 1)
            k_ln<<<cdiv(N, 4), 256, 0, stream>>>(obuf, lng, lnb, Ap, N);
    }
}

// Round 7
// 429.315 us; speedup vs baseline: 2.0090x; 1.1480x over previous
//
#include <hip/hip_runtime.h>
#include <hip/hip_bf16.h>

typedef short bf16x8 __attribute__((ext_vector_type(8)));
typedef float f32x4 __attribute__((ext_vector_type(4)));

static inline int cdiv(int a, int b){ return (a + b - 1) / b; }

// ---------------- target count histogram (1 atomic/edge) ----------------
__global__ void k_cnt(const int* __restrict__ tgt, int* __restrict__ cnt, int E){
    int e = blockIdx.x * 256 + threadIdx.x;
    if (e >= E) return;
    atomicAdd(&cnt[tgt[e]], 1);
}

// ---------------- 3-kernel exclusive scan over cnt[N] -> rs (+nxt) ----------------
__global__ void k_scan1(const int* __restrict__ cnt, int* __restrict__ rs,
                        int* __restrict__ bsum, int N){
    __shared__ int s[256];
    int i = blockIdx.x * 256 + threadIdx.x;
    int v = (i < N) ? cnt[i] : 0;
    s[threadIdx.x] = v;
    __syncthreads();
    for (int off = 1; off < 256; off <<= 1){
        int t = (threadIdx.x >= off) ? s[threadIdx.x - off] : 0;
        __syncthreads();
        s[threadIdx.x] += t;
        __syncthreads();
    }
    if (i < N) rs[i] = s[threadIdx.x] - v;      // exclusive
    if (threadIdx.x == 255) bsum[blockIdx.x] = s[255];
}

__global__ void k_scan2(int* __restrict__ bsum, int nb){  // nb <= 256
    __shared__ int s[256];
    int v = (threadIdx.x < nb) ? bsum[threadIdx.x] : 0;
    s[threadIdx.x] = v;
    __syncthreads();
    for (int off = 1; off < 256; off <<= 1){
        int t = (threadIdx.x >= off) ? s[threadIdx.x - off] : 0;
        __syncthreads();
        s[threadIdx.x] += t;
        __syncthreads();
    }
    if (threadIdx.x < nb) bsum[threadIdx.x] = s[threadIdx.x] - v;  // exclusive
}

__global__ void k_scan3(int* __restrict__ rs, int* __restrict__ nxt,
                        const int* __restrict__ bsum, int N, int E){
    int i = blockIdx.x * 256 + threadIdx.x;
    if (i < N){
        int v = rs[i] + bsum[blockIdx.x];
        rs[i] = v;
        nxt[i] = v;
    }
    if (i == 0) rs[N] = E;
}

// ---------------- scatter edges into CSR order: one float4 {eff0,eff1,eff2,src} ----
__global__ void k_scatter(const int* __restrict__ src, const int* __restrict__ tgt,
                          const float* __restrict__ asp,
                          const float* __restrict__ actx,
                          const float* __restrict__ alat,
                          const float* __restrict__ wsp,
                          const float* __restrict__ wctx,
                          const float* __restrict__ wlat,
                          int* __restrict__ nxt,
                          float4* __restrict__ effo4, int E){
    int e = blockIdx.x * 256 + threadIdx.x;
    if (e >= E) return;
    int t = tgt[e];
    int pos = atomicAdd(&nxt[t], 1);
    float4 v;
    v.x = asp[e]  * wsp[e];
    v.y = actx[e] * wctx[e];
    v.z = alat[e] * wlat[e];
    v.w = __int_as_float(src[e]);
    effo4[pos] = v;
}

// ---------------- deg: thread-per-node segment sum; dinv for all layers ----------
// (wave-per-node regressed: 1-lane powf + 64-wide butterfly for ~20-edge segments
//  = VALUBusy 100% at 78 us. Thread-per-node runs powf on all 64 lanes.)
__global__ __launch_bounds__(256) void k_deg(
        const float4* __restrict__ effo4, const int* __restrict__ rs,
        const float* __restrict__ dp,        // deg_power [L*3] fp32
        float* __restrict__ dinv_all,        // [L][N][3]
        int N, int L){
    int n = blockIdx.x * 256 + threadIdx.x;
    if (n >= N) return;
    int beg = rs[n], end = rs[n + 1];
    float s0 = 0.f, s1 = 0.f, s2 = 0.f;
    for (int i = beg; i < end; ++i){
        float4 v = effo4[i];
        s0 += v.x; s1 += v.y; s2 += v.z;
    }
    float d0 = fmaxf(1.f + s0, 1e-6f);
    float d1 = fmaxf(1.f + s1, 1e-6f);
    float d2 = fmaxf(1.f + s2, 1e-6f);
    for (int l = 0; l < L; ++l){
        size_t base = ((size_t)l * N + n) * 3;
        dinv_all[base + 0] = powf(d0, dp[l * 3 + 0]);
        dinv_all[base + 1] = powf(d1, dp[l * 3 + 1]);
        dinv_all[base + 2] = powf(d2, dp[l * 3 + 2]);
    }
}

// ---------------- per-layer: nv[e] = {eff_c * dinv_c[src], src_bits} ----------
__global__ void k_normv(const float4* __restrict__ effo4,
                        const float* __restrict__ dinv,  // this layer [N][3]
                        float4* __restrict__ nv, int E){
    int e = blockIdx.x * 256 + threadIdx.x;
    if (e >= E) return;
    float4 v = effo4[e];
    int s = __float_as_int(v.w);
    float4 o;
    o.x = v.x * dinv[3 * s + 0];
    o.y = v.y * dinv[3 * s + 1];
    o.z = v.z * dinv[3 * s + 2];
    o.w = v.w;
    nv[e] = o;
}

// ---------------- x (fp32) -> A'[:,0:128] (bf16, row stride 512) ----------------
__global__ void k_x2bf(const float* __restrict__ x, __hip_bfloat16* __restrict__ Ap, int n){
    int i = blockIdx.x * 256 + threadIdx.x;
    if (i < n) Ap[(size_t)(i >> 7) * 512 + (i & 127)] = __float2bfloat16(x[i]);
}

// ---------------- build BT[128][512]: B[k,j] = [W_self; W3[0..2]][k][j] ----------
__global__ void k_wcat(const float* __restrict__ Wself,  // [128,128] (k,j)
                       const float* __restrict__ W3,     // [3,128,128]
                       __hip_bfloat16* __restrict__ BT){ // [j][k] = [128][512]
    int i = blockIdx.x * 256 + threadIdx.x;  // 65536
    int j = i >> 9, k = i & 511;
    float v;
    if (k < 128) v = Wself[k * 128 + j];
    else {
        int c = (k >> 7) - 1, kk = k & 127;
        v = W3[(c * 128 + kk) * 128 + j];
    }
    BT[i] = __float2bfloat16(v);
}

// ---------------- aggregate: Y_c[t] = dt_c * sum_e nv_c[e] * x[src[e]] ----------
__global__ __launch_bounds__(256) void k_msg(
        __hip_bfloat16* __restrict__ Ap,   // [N,512]: cols 0..127 = x (read), 128..511 = Y (write)
        const float4* __restrict__ nv,     // [E] {n0,n1,n2,src_bits} CSR order
        const int* __restrict__ rs,        // [N+1]
        const float* __restrict__ dinv,    // [N,3] (this layer)
        int N){
    int w = threadIdx.x >> 6, lane = threadIdx.x & 63;
    int t = blockIdx.x * 4 + w;
    if (t >= N) return;
    float ax0 = 0.f, ay0 = 0.f, ax1 = 0.f, ay1 = 0.f, ax2 = 0.f, ay2 = 0.f;
    int beg = rs[t], end = rs[t + 1];
    int i = beg;
    for (; i + 4 <= end; i += 4){
        float4 n0 = nv[i], n1 = nv[i + 1], n2 = nv[i + 2], n3 = nv[i + 3];
        const __hip_bfloat162* p0 = (const __hip_bfloat162*)(Ap + (size_t)__float_as_int(n0.w) * 512);
        const __hip_bfloat162* p1 = (const __hip_bfloat162*)(Ap + (size_t)__float_as_int(n1.w) * 512);
        const __hip_bfloat162* p2 = (const __hip_bfloat162*)(Ap + (size_t)__float_as_int(n2.w) * 512);
        const __hip_bfloat162* p3 = (const __hip_bfloat162*)(Ap + (size_t)__float_as_int(n3.w) * 512);
        __hip_bfloat162 v0 = p0[lane], v1 = p1[lane], v2 = p2[lane], v3 = p3[lane];
        float2 f0 = __bfloat1622float2(v0);
        float2 f1 = __bfloat1622float2(v1);
        float2 f2 = __bfloat1622float2(v2);
        float2 f3 = __bfloat1622float2(v3);
        ax0 += n0.x * f0.x; ay0 += n0.x * f0.y;
        ax1 += n0.y * f0.x; ay1 += n0.y * f0.y;
        ax2 += n0.z * f0.x; ay2 += n0.z * f0.y;
        ax0 += n1.x * f1.x; ay0 += n1.x * f1.y;
        ax1 += n1.y * f1.x; ay1 += n1.y * f1.y;
        ax2 += n1.z * f1.x; ay2 += n1.z * f1.y;
        ax0 += n2.x * f2.x; ay0 += n2.x * f2.y;
        ax1 += n2.y * f2.x; ay1 += n2.y * f2.y;
        ax2 += n2.z * f2.x; ay2 += n2.z * f2.y;
        ax0 += n3.x * f3.x; ay0 += n3.x * f3.y;
        ax1 += n3.y * f3.x; ay1 += n3.y * f3.y;
        ax2 += n3.z * f3.x; ay2 += n3.z * f3.y;
    }
    for (; i < end; ++i){
        float4 n0 = nv[i];
        const __hip_bfloat162* p0 = (const __hip_bfloat162*)(Ap + (size_t)__float_as_int(n0.w) * 512);
        float2 f0 = __bfloat1622float2(p0[lane]);
        ax0 += n0.x * f0.x; ay0 += n0.x * f0.y;
        ax1 += n0.y * f0.x; ay1 += n0.y * f0.y;
        ax2 += n0.z * f0.x; ay2 += n0.z * f0.y;
    }
    float dt0 = dinv[3 * t], dt1 = dinv[3 * t + 1], dt2 = dinv[3 * t + 2];
    __hip_bfloat162* yo = (__hip_bfloat162*)(Ap + (size_t)t * 512 + 128) + lane;
    float2 r0 = {dt0 * ax0, dt0 * ay0};
    float2 r1 = {dt1 * ax1, dt1 * ay1};
    float2 r2 = {dt2 * ax2, dt2 * ay2};
    yo[0]   = __float22bfloat162_rn(r0);
    yo[64]  = __float22bfloat162_rn(r1);
    yo[128] = __float22bfloat162_rn(r2);
}

// ---------------- GEMM: out[M,128] = A'[M,512] @ B[512,128] + bias ----------
__global__ __launch_bounds__(256) void k_gemm(
        const __hip_bfloat16* __restrict__ A,   // [M,512] bf16
        const __hip_bfloat16* __restrict__ BT,  // [128,512] bf16 ([j][k])
        const float* __restrict__ bias,         // [128] fp32
        float* __restrict__ outbuf,             // [M,128]
        int M){
    __shared__ __hip_bfloat16 As[128 * 128];
    __shared__ __hip_bfloat16 Bs[128 * 128];
    const int tid = threadIdx.x;
    const int row0 = blockIdx.x * 128;
    const int w = tid >> 6, lane = tid & 63;
    const int wm = (w & 1) * 64, wn = (w >> 1) * 64;
    const int lm = lane & 15, lq = lane >> 4;

    f32x4 acc[4][4];
    #pragma unroll
    for (int mt = 0; mt < 4; ++mt)
        #pragma unroll
        for (int nt = 0; nt < 4; ++nt)
            acc[mt][nt] = {0.f, 0.f, 0.f, 0.f};

    for (int kt = 0; kt < 4; ++kt){
        // stage K-tile: 16B chunks, XOR-swizzled by (row&15)
        #pragma unroll
        for (int it = 0; it < 8; ++it){
            int v = it * 256 + tid;
            int r = v >> 4, c = v & 15;
            int soff = r * 128 + ((c ^ (r & 15)) << 3);
            int4 av = {0, 0, 0, 0};
            if (row0 + r < M)
                av = *(const int4*)(A + (size_t)(row0 + r) * 512 + kt * 128 + (c << 3));
            *(int4*)(&As[soff]) = av;
            int4 bv = *(const int4*)(BT + (size_t)r * 512 + kt * 128 + (c << 3));
            *(int4*)(&Bs[soff]) = bv;
        }
        __syncthreads();

        #pragma unroll
        for (int kk = 0; kk < 4; ++kk){
            int kc = kk * 4 + lq;  // 16B-chunk index along local K
            bf16x8 a[4], b[4];
            #pragma unroll
            for (int mt = 0; mt < 4; ++mt){
                int r = wm + mt * 16 + lm;
                a[mt] = *(const bf16x8*)(&As[r * 128 + ((kc ^ (r & 15)) << 3)]);
            }
            #pragma unroll
            for (int nt = 0; nt < 4; ++nt){
                int r = wn + nt * 16 + lm;
                b[nt] = *(const bf16x8*)(&Bs[r * 128 + ((kc ^ (r & 15)) << 3)]);
            }
            #pragma unroll
            for (int mt = 0; mt < 4; ++mt)
                #pragma unroll
                for (int nt = 0; nt < 4; ++nt)
                    acc[mt][nt] = __builtin_amdgcn_mfma_f32_16x16x32_bf16(
                        a[mt], b[nt], acc[mt][nt], 0, 0, 0);
        }
        __syncthreads();
    }

    // epilogue: D[row = lq*4 + reg][col = lm] per 16x16 fragment
    #pragma unroll
    for (int mt = 0; mt < 4; ++mt){
        #pragma unroll
        for (int nt = 0; nt < 4; ++nt){
            int col = wn + nt * 16 + lm;
            #pragma unroll
            for (int r = 0; r < 4; ++r){
                int row = row0 + wm + mt * 16 + lq * 4 + r;
                if (row < M)
                    outbuf[(size_t)row * 128 + col] = acc[mt][nt][r] + bias[col];
            }
        }
    }
}

// ---------------- LayerNorm + ReLU -> bf16 into A'[:,0:128] ----------------
__global__ __launch_bounds__(256) void k_ln(
        const float* __restrict__ outbuf,
        const float* __restrict__ g,
        const float* __restrict__ b,
        __hip_bfloat16* __restrict__ Ap, int N){
    int w = threadIdx.x >> 6, lane = threadIdx.x & 63;
    int t = blockIdx.x * 4 + w;
    if (t >= N) return;
    const float* row = outbuf + (size_t)t * 128;
    float x0 = row[2 * lane], x1 = row[2 * lane + 1];
    float s = x0 + x1;
    #pragma unroll
    for (int off = 32; off; off >>= 1) s += __shfl_xor(s, off);
    float mu = s * (1.0f / 128.0f);
    float d0 = x0 - mu, d1 = x1 - mu;
    float ss = d0 * d0 + d1 * d1;
    #pragma unroll
    for (int off = 32; off; off >>= 1) ss += __shfl_xor(ss, off);
    float r = rsqrtf(ss * (1.0f / 128.0f) + 1e-5f);
    float y0 = fmaxf(d0 * r * g[2 * lane]     + b[2 * lane],     0.0f);
    float y1 = fmaxf(d1 * r * g[2 * lane + 1] + b[2 * lane + 1], 0.0f);
    float2 y = {y0, y1};
    *((__hip_bfloat162*)(Ap + (size_t)t * 512) + lane) = __float22bfloat162_rn(y);
}

extern "C" void kernel_launch(void* const* d_in, const int* in_sizes, int n_in,
                              void* d_out, int out_size, void* d_ws, size_t ws_size,
                              hipStream_t stream) {
    const float* x     = (const float*)d_in[0];
    const int*   ei    = (const int*)d_in[1];
    const float* asp   = (const float*)d_in[2];
    const float* actx  = (const float*)d_in[3];
    const float* alat  = (const float*)d_in[4];
    const float* wsp   = (const float*)d_in[5];
    const float* wctx  = (const float*)d_in[6];
    const float* wlat  = (const float*)d_in[7];
    const float* W3    = (const float*)d_in[8];
    const float* Wself = (const float*)d_in[9];
    const float* bias  = (const float*)d_in[10];
    const float* dpow  = (const float*)d_in[11];
    const float* lng   = (const float*)d_in[12];
    const float* lnb   = (const float*)d_in[13];

    const int N = in_sizes[0] / 128;
    const int E = in_sizes[1] / 2;
    const int L = in_sizes[8] / (3 * 128 * 128);
    const int* src = ei;
    const int* tgt = ei + E;

    // workspace carve (256B-aligned)
    char* p = (char*)d_ws;
    auto alloc = [&](size_t bytes) -> void* {
        void* r = (void*)p;
        p += (bytes + 255) & ~(size_t)255;
        return r;
    };
    int*    cnt      = (int*)   alloc((size_t)N * 4);
    int*    rs       = (int*)   alloc((size_t)(N + 1) * 4);
    int*    nxt      = (int*)   alloc((size_t)N * 4);
    int*    bsum     = (int*)   alloc(1024);
    float4* effo4    = (float4*)alloc((size_t)E * 16);
    float4* nv       = (float4*)alloc((size_t)E * 16);
    float*  dinv_all = (float*) alloc((size_t)L * N * 3 * 4);
    float*  outbuf   = (float*) alloc((size_t)N * 128 * 4);
    __hip_bfloat16* Ap = (__hip_bfloat16*)alloc((size_t)N * 512 * 2);  // [x|Y0|Y1|Y2]
    __hip_bfloat16* BT = (__hip_bfloat16*)alloc((size_t)128 * 512 * 2);

    const int nb = cdiv(N, 256);  // scan blocks (<=256 for N<=65536)

    // ---- prep: CSR by target (2M atomics total), deg/dinv, x->A' ----
    hipMemsetAsync(cnt, 0, (size_t)N * 4, stream);
    k_cnt    <<<cdiv(E, 256), 256, 0, stream>>>(tgt, cnt, E);
    k_scan1  <<<nb, 256, 0, stream>>>(cnt, rs, bsum, N);
    k_scan2  <<<1,  256, 0, stream>>>(bsum, nb);
    k_scan3  <<<nb, 256, 0, stream>>>(rs, nxt, bsum, N, E);
    k_scatter<<<cdiv(E, 256), 256, 0, stream>>>(src, tgt, asp, actx, alat, wsp, wctx, wlat,
                                                nxt, effo4, E);
    k_deg    <<<cdiv(N, 256), 256, 0, stream>>>(effo4, rs, dpow, dinv_all, N, L);
    k_x2bf   <<<cdiv(N * 128, 256), 256, 0, stream>>>(x, Ap, N * 128);

    // ---- layers ----
    for (int l = 0; l < L; ++l){
        float* obuf = (l == L - 1) ? (float*)d_out : outbuf;
        const float* dinv_l = dinv_all + (size_t)l * N * 3;
        k_normv<<<cdiv(E, 256), 256, 0, stream>>>(effo4, dinv_l, nv, E);
        k_msg  <<<cdiv(N, 4), 256, 0, stream>>>(Ap, nv, rs, dinv_l, N);
        k_wcat <<<256, 256, 0, stream>>>(Wself + (size_t)l * 128 * 128,
                                         W3 + (size_t)l * 3 * 128 * 128, BT);
        k_gemm <<<cdiv(N, 128), 256, 0, stream>>>(Ap, BT, bias + l * 128, obuf, N);
        if (l < L - 1)
            k_ln<<<cdiv(N, 4), 256, 0, stream>>>(obuf, lng, lnb, Ap, N);
    }
}

// Round 8
// 416.750 us; speedup vs baseline: 2.0695x; 1.0301x over previous
//
#include <hip/hip_runtime.h>
#include <hip/hip_bf16.h>

typedef short bf16x8 __attribute__((ext_vector_type(8)));
typedef float f32x4 __attribute__((ext_vector_type(4)));

static inline int cdiv(int a, int b){ return (a + b - 1) / b; }

__device__ __forceinline__ unsigned pack_bf16_hi(float v){
    // round-to-nearest bf16, return bits in high 16
    return ((unsigned)__bfloat16_as_ushort(__float2bfloat16(v))) << 16;
}
__device__ __forceinline__ float bf16hi_to_f32(unsigned bits_hi16){
    return __uint_as_float(bits_hi16);  // bf16 bits already in [31:16]
}

// ---------------- target count histogram: 4 edges/thread ----------------
__global__ void k_cnt(const int* __restrict__ tgt, int* __restrict__ cnt, int E){
    int e0 = (blockIdx.x * 256 + threadIdx.x) * 4;
    if (e0 + 3 < E){
        int4 t = *(const int4*)(tgt + e0);
        atomicAdd(&cnt[t.x], 1);
        atomicAdd(&cnt[t.y], 1);
        atomicAdd(&cnt[t.z], 1);
        atomicAdd(&cnt[t.w], 1);
    } else {
        for (int e = e0; e < E; ++e) atomicAdd(&cnt[tgt[e]], 1);
    }
}

// ---------------- 3-kernel exclusive scan over cnt[N] -> rs (+nxt) ----------------
__global__ void k_scan1(const int* __restrict__ cnt, int* __restrict__ rs,
                        int* __restrict__ bsum, int N){
    __shared__ int s[256];
    int i = blockIdx.x * 256 + threadIdx.x;
    int v = (i < N) ? cnt[i] : 0;
    s[threadIdx.x] = v;
    __syncthreads();
    for (int off = 1; off < 256; off <<= 1){
        int t = (threadIdx.x >= off) ? s[threadIdx.x - off] : 0;
        __syncthreads();
        s[threadIdx.x] += t;
        __syncthreads();
    }
    if (i < N) rs[i] = s[threadIdx.x] - v;      // exclusive
    if (threadIdx.x == 255) bsum[blockIdx.x] = s[255];
}

__global__ void k_scan2(int* __restrict__ bsum, int nb){  // nb <= 256
    __shared__ int s[256];
    int v = (threadIdx.x < nb) ? bsum[threadIdx.x] : 0;
    s[threadIdx.x] = v;
    __syncthreads();
    for (int off = 1; off < 256; off <<= 1){
        int t = (threadIdx.x >= off) ? s[threadIdx.x - off] : 0;
        __syncthreads();
        s[threadIdx.x] += t;
        __syncthreads();
    }
    if (threadIdx.x < nb) bsum[threadIdx.x] = s[threadIdx.x] - v;  // exclusive
}

__global__ void k_scan3(int* __restrict__ rs, int* __restrict__ nxt,
                        const int* __restrict__ bsum, int N, int E){
    int i = blockIdx.x * 256 + threadIdx.x;
    if (i < N){
        int v = rs[i] + bsum[blockIdx.x];
        rs[i] = v;
        nxt[i] = v;
    }
    if (i == 0) rs[N] = E;
}

// ---------------- scatter into CSR order: packed 8B {src:16|eff0:bf16, eff1|eff2} ----
// NOTE: requires N <= 65536 (src fits u16); problem has N=50000.
__global__ void k_scatter(const int* __restrict__ src, const int* __restrict__ tgt,
                          const float* __restrict__ asp,
                          const float* __restrict__ actx,
                          const float* __restrict__ alat,
                          const float* __restrict__ wsp,
                          const float* __restrict__ wctx,
                          const float* __restrict__ wlat,
                          int* __restrict__ nxt,
                          uint2* __restrict__ effo, int E){
    int e = blockIdx.x * 256 + threadIdx.x;
    if (e >= E) return;
    int t = tgt[e];
    int pos = atomicAdd(&nxt[t], 1);
    uint2 v;
    v.x = (unsigned)src[e] | pack_bf16_hi(asp[e] * wsp[e]);
    v.y = (pack_bf16_hi(actx[e] * wctx[e]) >> 16) | pack_bf16_hi(alat[e] * wlat[e]);
    effo[pos] = v;
}

// ---------------- deg: thread-per-node segment sum; dinv for all layers ----------
__global__ __launch_bounds__(256) void k_deg(
        const uint2* __restrict__ effo, const int* __restrict__ rs,
        const float* __restrict__ dp,        // deg_power [L*3] fp32
        float* __restrict__ dinv_all,        // [L][N][3]
        int N, int L){
    int n = blockIdx.x * 256 + threadIdx.x;
    if (n >= N) return;
    int beg = rs[n], end = rs[n + 1];
    float s0 = 0.f, s1 = 0.f, s2 = 0.f;
    for (int i = beg; i < end; ++i){
        uint2 v = effo[i];
        s0 += bf16hi_to_f32(v.x & 0xFFFF0000u);
        s1 += bf16hi_to_f32(v.y << 16);
        s2 += bf16hi_to_f32(v.y & 0xFFFF0000u);
    }
    float d0 = fmaxf(1.f + s0, 1e-6f);
    float d1 = fmaxf(1.f + s1, 1e-6f);
    float d2 = fmaxf(1.f + s2, 1e-6f);
    for (int l = 0; l < L; ++l){
        size_t base = ((size_t)l * N + n) * 3;
        dinv_all[base + 0] = powf(d0, dp[l * 3 + 0]);
        dinv_all[base + 1] = powf(d1, dp[l * 3 + 1]);
        dinv_all[base + 2] = powf(d2, dp[l * 3 + 2]);
    }
}

// ---------------- nv for ALL layers: nv[l*E+e] = {src, eff_c * dinv_c[l][src]} ----
__global__ void k_normv(const uint2* __restrict__ effo,
                        const float* __restrict__ dinv_all,  // [L][N][3]
                        uint2* __restrict__ nv, int E, int N, int L){
    int i = blockIdx.x * 256 + threadIdx.x;
    if (i >= L * E) return;
    int l = i / E;
    int e = i - l * E;
    const float* dinv = dinv_all + (size_t)l * N * 3;
    uint2 v = effo[e];
    unsigned s = v.x & 0xFFFFu;
    float e0 = bf16hi_to_f32(v.x & 0xFFFF0000u);
    float e1 = bf16hi_to_f32(v.y << 16);
    float e2 = bf16hi_to_f32(v.y & 0xFFFF0000u);
    float n0 = e0 * dinv[3 * s + 0];
    float n1 = e1 * dinv[3 * s + 1];
    float n2 = e2 * dinv[3 * s + 2];
    uint2 o;
    o.x = s | pack_bf16_hi(n0);
    o.y = (pack_bf16_hi(n1) >> 16) | pack_bf16_hi(n2);
    nv[i] = o;
}

// ---------------- x (fp32) -> A'[:,0:128] (bf16, row stride 512) ----------------
__global__ void k_x2bf(const float* __restrict__ x, __hip_bfloat16* __restrict__ Ap, int n){
    int i = blockIdx.x * 256 + threadIdx.x;
    if (i < n) Ap[(size_t)(i >> 7) * 512 + (i & 127)] = __float2bfloat16(x[i]);
}

// ---------------- BT for ALL layers: BT[l][j][k], B = [W_self; W3[0..2]] ----------
__global__ void k_wcat(const float* __restrict__ Wself,  // [L,128,128] (k,j)
                       const float* __restrict__ W3,     // [L,3,128,128]
                       __hip_bfloat16* __restrict__ BT,  // [L][128][512]
                       int L){
    int i = blockIdx.x * 256 + threadIdx.x;
    if (i >= L * 65536) return;
    int l = i >> 16, r = i & 65535;
    int j = r >> 9, k = r & 511;
    float v;
    if (k < 128) v = Wself[l * 16384 + k * 128 + j];
    else {
        int c = (k >> 7) - 1, kk = k & 127;
        v = W3[l * 49152 + (c * 128 + kk) * 128 + j];
    }
    BT[i] = __float2bfloat16(v);
}

// ---------------- aggregate: Y_c[t] = dt_c * sum_e nv_c[e] * x[src[e]] ----------
// packed 8B nv; unroll 8 => 16 loads in flight per wave
__global__ __launch_bounds__(256) void k_msg(
        __hip_bfloat16* __restrict__ Ap,   // [N,512]: cols 0..127 = x (read), 128..511 = Y (write)
        const uint2* __restrict__ nv,      // [E] packed, CSR order (this layer)
        const int* __restrict__ rs,        // [N+1]
        const float* __restrict__ dinv,    // [N,3] (this layer)
        int N){
    int w = threadIdx.x >> 6, lane = threadIdx.x & 63;
    int t = blockIdx.x * 4 + w;
    if (t >= N) return;
    float ax0 = 0.f, ay0 = 0.f, ax1 = 0.f, ay1 = 0.f, ax2 = 0.f, ay2 = 0.f;
    int beg = rs[t], end = rs[t + 1];
    int i = beg;
    for (; i + 8 <= end; i += 8){
        uint2 m[8];
        #pragma unroll
        for (int u = 0; u < 8; ++u) m[u] = nv[i + u];
        float2 f[8];
        #pragma unroll
        for (int u = 0; u < 8; ++u){
            const __hip_bfloat162* p =
                (const __hip_bfloat162*)(Ap + (size_t)(m[u].x & 0xFFFFu) * 512);
            f[u] = __bfloat1622float2(p[lane]);
        }
        #pragma unroll
        for (int u = 0; u < 8; ++u){
            float n0 = bf16hi_to_f32(m[u].x & 0xFFFF0000u);
            float n1 = bf16hi_to_f32(m[u].y << 16);
            float n2 = bf16hi_to_f32(m[u].y & 0xFFFF0000u);
            ax0 += n0 * f[u].x; ay0 += n0 * f[u].y;
            ax1 += n1 * f[u].x; ay1 += n1 * f[u].y;
            ax2 += n2 * f[u].x; ay2 += n2 * f[u].y;
        }
    }
    for (; i < end; ++i){
        uint2 m = nv[i];
        const __hip_bfloat162* p =
            (const __hip_bfloat162*)(Ap + (size_t)(m.x & 0xFFFFu) * 512);
        float2 fv = __bfloat1622float2(p[lane]);
        float n0 = bf16hi_to_f32(m.x & 0xFFFF0000u);
        float n1 = bf16hi_to_f32(m.y << 16);
        float n2 = bf16hi_to_f32(m.y & 0xFFFF0000u);
        ax0 += n0 * fv.x; ay0 += n0 * fv.y;
        ax1 += n1 * fv.x; ay1 += n1 * fv.y;
        ax2 += n2 * fv.x; ay2 += n2 * fv.y;
    }
    float dt0 = dinv[3 * t], dt1 = dinv[3 * t + 1], dt2 = dinv[3 * t + 2];
    __hip_bfloat162* yo = (__hip_bfloat162*)(Ap + (size_t)t * 512 + 128) + lane;
    float2 r0 = {dt0 * ax0, dt0 * ay0};
    float2 r1 = {dt1 * ax1, dt1 * ay1};
    float2 r2 = {dt2 * ax2, dt2 * ay2};
    yo[0]   = __float22bfloat162_rn(r0);
    yo[64]  = __float22bfloat162_rn(r1);
    yo[128] = __float22bfloat162_rn(r2);
}

// ---------------- GEMM: out[M,128] = A'[M,512] @ B[512,128] + bias ----------
__global__ __launch_bounds__(256) void k_gemm(
        const __hip_bfloat16* __restrict__ A,   // [M,512] bf16
        const __hip_bfloat16* __restrict__ BT,  // [128,512] bf16 ([j][k])
        const float* __restrict__ bias,         // [128] fp32
        float* __restrict__ outbuf,             // [M,128]
        int M){
    __shared__ __hip_bfloat16 As[128 * 128];
    __shared__ __hip_bfloat16 Bs[128 * 128];
    const int tid = threadIdx.x;
    const int row0 = blockIdx.x * 128;
    const int w = tid >> 6, lane = tid & 63;
    const int wm = (w & 1) * 64, wn = (w >> 1) * 64;
    const int lm = lane & 15, lq = lane >> 4;

    f32x4 acc[4][4];
    #pragma unroll
    for (int mt = 0; mt < 4; ++mt)
        #pragma unroll
        for (int nt = 0; nt < 4; ++nt)
            acc[mt][nt] = {0.f, 0.f, 0.f, 0.f};

    for (int kt = 0; kt < 4; ++kt){
        #pragma unroll
        for (int it = 0; it < 8; ++it){
            int v = it * 256 + tid;
            int r = v >> 4, c = v & 15;
            int soff = r * 128 + ((c ^ (r & 15)) << 3);
            int4 av = {0, 0, 0, 0};
            if (row0 + r < M)
                av = *(const int4*)(A + (size_t)(row0 + r) * 512 + kt * 128 + (c << 3));
            *(int4*)(&As[soff]) = av;
            int4 bv = *(const int4*)(BT + (size_t)r * 512 + kt * 128 + (c << 3));
            *(int4*)(&Bs[soff]) = bv;
        }
        __syncthreads();

        #pragma unroll
        for (int kk = 0; kk < 4; ++kk){
            int kc = kk * 4 + lq;
            bf16x8 a[4], b[4];
            #pragma unroll
            for (int mt = 0; mt < 4; ++mt){
                int r = wm + mt * 16 + lm;
                a[mt] = *(const bf16x8*)(&As[r * 128 + ((kc ^ (r & 15)) << 3)]);
            }
            #pragma unroll
            for (int nt = 0; nt < 4; ++nt){
                int r = wn + nt * 16 + lm;
                b[nt] = *(const bf16x8*)(&Bs[r * 128 + ((kc ^ (r & 15)) << 3)]);
            }
            #pragma unroll
            for (int mt = 0; mt < 4; ++mt)
                #pragma unroll
                for (int nt = 0; nt < 4; ++nt)
                    acc[mt][nt] = __builtin_amdgcn_mfma_f32_16x16x32_bf16(
                        a[mt], b[nt], acc[mt][nt], 0, 0, 0);
        }
        __syncthreads();
    }

    #pragma unroll
    for (int mt = 0; mt < 4; ++mt){
        #pragma unroll
        for (int nt = 0; nt < 4; ++nt){
            int col = wn + nt * 16 + lm;
            #pragma unroll
            for (int r = 0; r < 4; ++r){
                int row = row0 + wm + mt * 16 + lq * 4 + r;
                if (row < M)
                    outbuf[(size_t)row * 128 + col] = acc[mt][nt][r] + bias[col];
            }
        }
    }
}

// ---------------- LayerNorm + ReLU -> bf16 into A'[:,0:128] ----------------
__global__ __launch_bounds__(256) void k_ln(
        const float* __restrict__ outbuf,
        const float* __restrict__ g,
        const float* __restrict__ b,
        __hip_bfloat16* __restrict__ Ap, int N){
    int w = threadIdx.x >> 6, lane = threadIdx.x & 63;
    int t = blockIdx.x * 4 + w;
    if (t >= N) return;
    const float* row = outbuf + (size_t)t * 128;
    float x0 = row[2 * lane], x1 = row[2 * lane + 1];
    float s = x0 + x1;
    #pragma unroll
    for (int off = 32; off; off >>= 1) s += __shfl_xor(s, off);
    float mu = s * (1.0f / 128.0f);
    float d0 = x0 - mu, d1 = x1 - mu;
    float ss = d0 * d0 + d1 * d1;
    #pragma unroll
    for (int off = 32; off; off >>= 1) ss += __shfl_xor(ss, off);
    float r = rsqrtf(ss * (1.0f / 128.0f) + 1e-5f);
    float y0 = fmaxf(d0 * r * g[2 * lane]     + b[2 * lane],     0.0f);
    float y1 = fmaxf(d1 * r * g[2 * lane + 1] + b[2 * lane + 1], 0.0f);
    float2 y = {y0, y1};
    *((__hip_bfloat162*)(Ap + (size_t)t * 512) + lane) = __float22bfloat162_rn(y);
}

extern "C" void kernel_launch(void* const* d_in, const int* in_sizes, int n_in,
                              void* d_out, int out_size, void* d_ws, size_t ws_size,
                              hipStream_t stream) {
    const float* x     = (const float*)d_in[0];
    const int*   ei    = (const int*)d_in[1];
    const float* asp   = (const float*)d_in[2];
    const float* actx  = (const float*)d_in[3];
    const float* alat  = (const float*)d_in[4];
    const float* wsp   = (const float*)d_in[5];
    const float* wctx  = (const float*)d_in[6];
    const float* wlat  = (const float*)d_in[7];
    const float* W3    = (const float*)d_in[8];
    const float* Wself = (const float*)d_in[9];
    const float* bias  = (const float*)d_in[10];
    const float* dpow  = (const float*)d_in[11];
    const float* lng   = (const float*)d_in[12];
    const float* lnb   = (const float*)d_in[13];

    const int N = in_sizes[0] / 128;
    const int E = in_sizes[1] / 2;
    const int L = in_sizes[8] / (3 * 128 * 128);
    const int* src = ei;
    const int* tgt = ei + E;

    // workspace carve (256B-aligned)
    char* p = (char*)d_ws;
    auto alloc = [&](size_t bytes) -> void* {
        void* r = (void*)p;
        p += (bytes + 255) & ~(size_t)255;
        return r;
    };
    int*   cnt      = (int*)  alloc((size_t)N * 4);
    int*   rs       = (int*)  alloc((size_t)(N + 1) * 4);
    int*   nxt      = (int*)  alloc((size_t)N * 4);
    int*   bsum     = (int*)  alloc(1024);
    uint2* effo     = (uint2*)alloc((size_t)E * 8);
    uint2* nv       = (uint2*)alloc((size_t)L * E * 8);
    float* dinv_all = (float*)alloc((size_t)L * N * 3 * 4);
    float* outbuf   = (float*)alloc((size_t)N * 128 * 4);
    __hip_bfloat16* Ap = (__hip_bfloat16*)alloc((size_t)N * 512 * 2);  // [x|Y0|Y1|Y2]
    __hip_bfloat16* BT = (__hip_bfloat16*)alloc((size_t)L * 128 * 512 * 2);

    const int nb = cdiv(N, 256);  // scan blocks (<=256 for N<=65536)

    // ---- prep ----
    hipMemsetAsync(cnt, 0, (size_t)N * 4, stream);
    k_cnt    <<<cdiv(E, 1024), 256, 0, stream>>>(tgt, cnt, E);
    k_scan1  <<<nb, 256, 0, stream>>>(cnt, rs, bsum, N);
    k_scan2  <<<1,  256, 0, stream>>>(bsum, nb);
    k_scan3  <<<nb, 256, 0, stream>>>(rs, nxt, bsum, N, E);
    k_scatter<<<cdiv(E, 256), 256, 0, stream>>>(src, tgt, asp, actx, alat, wsp, wctx, wlat,
                                                nxt, effo, E);
    k_deg    <<<cdiv(N, 256), 256, 0, stream>>>(effo, rs, dpow, dinv_all, N, L);
    k_x2bf   <<<cdiv(N * 128, 256), 256, 0, stream>>>(x, Ap, N * 128);
    k_wcat   <<<cdiv(L * 65536, 256), 256, 0, stream>>>(Wself, W3, BT, L);
    k_normv  <<<cdiv(L * E, 256), 256, 0, stream>>>(effo, dinv_all, nv, E, N, L);

    // ---- layers ----
    for (int l = 0; l < L; ++l){
        float* obuf = (l == L - 1) ? (float*)d_out : outbuf;
        const float* dinv_l = dinv_all + (size_t)l * N * 3;
        k_msg  <<<cdiv(N, 4), 256, 0, stream>>>(Ap, nv + (size_t)l * E, rs, dinv_l, N);
        k_gemm <<<cdiv(N, 128), 256, 0, stream>>>(Ap, BT + (size_t)l * 65536,
                                                  bias + l * 128, obuf, N);
        if (l < L - 1)
            k_ln<<<cdiv(N, 4), 256, 0, stream>>>(obuf, lng, lnb, Ap, N);
    }
}

// Round 9
// 371.121 us; speedup vs baseline: 2.3240x; 1.1229x over previous
//
#include <hip/hip_runtime.h>
#include <hip/hip_bf16.h>

typedef short bf16x8 __attribute__((ext_vector_type(8)));
typedef float f32x4 __attribute__((ext_vector_type(4)));

#define BSH 7            // 128 targets per bucket
#define BK  (1 << BSH)

static inline int cdiv(int a, int b){ return (a + b - 1) / b; }

__device__ __forceinline__ unsigned pack_bf16_hi(float v){
    return ((unsigned)__bfloat16_as_ushort(__float2bfloat16(v))) << 16;
}
__device__ __forceinline__ float bf16hi_to_f32(unsigned bits_hi16){
    return __uint_as_float(bits_hi16);  // bf16 bits already in [31:16]
}

// ---------- pass 0: global bucket histogram (LDS-privatized) ----------
__global__ __launch_bounds__(256) void k_bcnt0(const int* __restrict__ tgt,
                                               int* __restrict__ gcnt, int E, int NB){
    __shared__ int lh[1024];
    int tid = threadIdx.x;
    for (int b = tid; b < 1024; b += 256) lh[b] = 0;
    __syncthreads();
    int c0 = blockIdx.x * 4096;
    #pragma unroll
    for (int u = 0; u < 16; ++u){
        int e = c0 + u * 256 + tid;
        if (e < E) atomicAdd(&lh[tgt[e] >> BSH], 1);
    }
    __syncthreads();
    for (int b = tid; b < NB; b += 256){
        int c = lh[b];
        if (c) atomicAdd(&gcnt[b], c);
    }
}

// ---------- pass 0.5: scan bucket counts -> bases (= CSR bucket bases) ----------
__global__ __launch_bounds__(256) void k_bscan(const int* __restrict__ gcnt,
                                               int* __restrict__ bbase,
                                               int* __restrict__ gcur,
                                               int* __restrict__ rs,
                                               int N, int E){
    __shared__ int sc[256];
    int tid = threadIdx.x;
    int b0 = tid * 4;
    int v0 = gcnt[b0], v1 = gcnt[b0 + 1], v2 = gcnt[b0 + 2], v3 = gcnt[b0 + 3];
    int t3 = v0 + v1 + v2 + v3;
    sc[tid] = t3;
    __syncthreads();
    for (int off = 1; off < 256; off <<= 1){
        int x = (tid >= off) ? sc[tid - off] : 0;
        __syncthreads();
        sc[tid] += x;
        __syncthreads();
    }
    int ex = sc[tid] - t3;
    bbase[b0]     = ex;
    bbase[b0 + 1] = ex + v0;
    bbase[b0 + 2] = ex + v0 + v1;
    bbase[b0 + 3] = ex + v0 + v1 + v2;
    gcur[b0] = bbase[b0]; gcur[b0 + 1] = bbase[b0 + 1];
    gcur[b0 + 2] = bbase[b0 + 2]; gcur[b0 + 3] = bbase[b0 + 3];
    if (tid == 255) bbase[1024] = sc[255];   // == E
    if (tid == 0)   rs[N] = E;
}

// ---------- pass 1: bin edges into bucket-contiguous regions via LDS staging ----------
__global__ __launch_bounds__(256) void k_bin(
        const int* __restrict__ src, const int* __restrict__ tgt,
        const float* __restrict__ asp, const float* __restrict__ actx,
        const float* __restrict__ alat, const float* __restrict__ wsp,
        const float* __restrict__ wctx, const float* __restrict__ wlat,
        int* __restrict__ gcur, uint4* __restrict__ binned, int E, int NB){
    __shared__ int lh[1024], lo[1024], lc[1024], gb[1024], tsum[256];
    __shared__ unsigned sx[4096], sy[4096];
    __shared__ int st[4096];
    int tid = threadIdx.x;
    int c0 = blockIdx.x * 4096;
    int cnt = E - c0; if (cnt > 4096) cnt = 4096;
    for (int b = tid; b < 1024; b += 256){ lh[b] = 0; lc[b] = 0; }
    __syncthreads();
    #pragma unroll
    for (int u = 0; u < 16; ++u){
        int e = c0 + u * 256 + tid;
        if (e < E) atomicAdd(&lh[tgt[e] >> BSH], 1);
    }
    __syncthreads();
    // exclusive scan lh -> lo (4 per thread + block scan)
    int b4 = tid * 4;
    int v0 = lh[b4], v1 = lh[b4 + 1], v2 = lh[b4 + 2], v3 = lh[b4 + 3];
    int t3 = v0 + v1 + v2 + v3;
    tsum[tid] = t3;
    __syncthreads();
    for (int off = 1; off < 256; off <<= 1){
        int x = (tid >= off) ? tsum[tid - off] : 0;
        __syncthreads();
        tsum[tid] += x;
        __syncthreads();
    }
    int ex = tsum[tid] - t3;
    lo[b4] = ex; lo[b4 + 1] = ex + v0; lo[b4 + 2] = ex + v0 + v1; lo[b4 + 3] = ex + v0 + v1 + v2;
    // reserve global ranges per bucket
    for (int b = tid; b < NB; b += 256){
        int c = lh[b];
        gb[b] = c ? atomicAdd(&gcur[b], c) : 0;
    }
    __syncthreads();
    // stage: group edges by bucket in LDS
    #pragma unroll
    for (int u = 0; u < 16; ++u){
        int e = c0 + u * 256 + tid;
        if (e < E){
            int t = tgt[e];
            int b = t >> BSH;
            int p = lo[b] + atomicAdd(&lc[b], 1);
            sx[p] = (unsigned)src[e] | pack_bf16_hi(asp[e] * wsp[e]);
            sy[p] = (pack_bf16_hi(actx[e] * wctx[e]) >> 16) | pack_bf16_hi(alat[e] * wlat[e]);
            st[p] = t;
        }
    }
    __syncthreads();
    // stream out: contiguous runs per bucket
    for (int i = tid; i < cnt; i += 256){
        int t = st[i];
        int b = t >> BSH;
        int g = gb[b] + (i - lo[b]);
        uint4 o = {sx[i], sy[i], (unsigned)t, 0u};
        binned[g] = o;
    }
}

// ---------- pass 2: per-bucket CSR finalize (writes rs + final effo) ----------
__global__ __launch_bounds__(256) void k_bucket(
        const uint4* __restrict__ binned, const int* __restrict__ bbase,
        uint2* __restrict__ effo, int* __restrict__ rs, int N){
    __shared__ int th[128], sc2[128], cur[128];
    int tid = threadIdx.x;
    int b = blockIdx.x;
    int t0 = b << BSH;
    int ebeg = bbase[b], eend = bbase[b + 1];
    if (tid < 128) th[tid] = 0;
    __syncthreads();
    for (int i = ebeg + tid; i < eend; i += 256)
        atomicAdd(&th[(int)binned[i].z - t0], 1);
    __syncthreads();
    int v = (tid < 128) ? th[tid] : 0;
    if (tid < 128) sc2[tid] = v;
    __syncthreads();
    for (int off = 1; off < 128; off <<= 1){
        int x = (tid >= off && tid < 128) ? sc2[tid - off] : 0;
        __syncthreads();
        if (tid < 128) sc2[tid] += x;
        __syncthreads();
    }
    if (tid < 128){
        int exv = sc2[tid] - v;
        cur[tid] = exv;
        int t = t0 + tid;
        if (t < N) rs[t] = ebeg + exv;
    }
    __syncthreads();
    for (int i = ebeg + tid; i < eend; i += 256){
        uint4 r = binned[i];
        int loc = (int)r.z - t0;
        int p = atomicAdd(&cur[loc], 1);
        uint2 o = {r.x, r.y};
        effo[ebeg + p] = o;
    }
}

// ---------------- deg: thread-per-node segment sum; dinv for all layers ----------
__global__ __launch_bounds__(256) void k_deg(
        const uint2* __restrict__ effo, const int* __restrict__ rs,
        const float* __restrict__ dp,        // deg_power [L*3] fp32
        float* __restrict__ dinv_all,        // [L][N][3]
        int N, int L){
    int n = blockIdx.x * 256 + threadIdx.x;
    if (n >= N) return;
    int beg = rs[n], end = rs[n + 1];
    float s0 = 0.f, s1 = 0.f, s2 = 0.f;
    for (int i = beg; i < end; ++i){
        uint2 v = effo[i];
        s0 += bf16hi_to_f32(v.x & 0xFFFF0000u);
        s1 += bf16hi_to_f32(v.y << 16);
        s2 += bf16hi_to_f32(v.y & 0xFFFF0000u);
    }
    float d0 = fmaxf(1.f + s0, 1e-6f);
    float d1 = fmaxf(1.f + s1, 1e-6f);
    float d2 = fmaxf(1.f + s2, 1e-6f);
    for (int l = 0; l < L; ++l){
        size_t base = ((size_t)l * N + n) * 3;
        dinv_all[base + 0] = powf(d0, dp[l * 3 + 0]);
        dinv_all[base + 1] = powf(d1, dp[l * 3 + 1]);
        dinv_all[base + 2] = powf(d2, dp[l * 3 + 2]);
    }
}

// ---------------- nv for ALL layers: nv[l*E+e] = {src, eff_c * dinv_c[l][src]} ----
__global__ void k_normv(const uint2* __restrict__ effo,
                        const float* __restrict__ dinv_all,  // [L][N][3]
                        uint2* __restrict__ nv, int E, int N, int L){
    int i = blockIdx.x * 256 + threadIdx.x;
    if (i >= L * E) return;
    int l = i / E;
    int e = i - l * E;
    const float* dinv = dinv_all + (size_t)l * N * 3;
    uint2 v = effo[e];
    unsigned s = v.x & 0xFFFFu;
    float e0 = bf16hi_to_f32(v.x & 0xFFFF0000u);
    float e1 = bf16hi_to_f32(v.y << 16);
    float e2 = bf16hi_to_f32(v.y & 0xFFFF0000u);
    float n0 = e0 * dinv[3 * s + 0];
    float n1 = e1 * dinv[3 * s + 1];
    float n2 = e2 * dinv[3 * s + 2];
    uint2 o;
    o.x = s | pack_bf16_hi(n0);
    o.y = (pack_bf16_hi(n1) >> 16) | pack_bf16_hi(n2);
    nv[i] = o;
}

// ---------------- x (fp32) -> A'[:,0:128] (bf16, row stride 512) ----------------
__global__ void k_x2bf(const float* __restrict__ x, __hip_bfloat16* __restrict__ Ap, int n){
    int i = blockIdx.x * 256 + threadIdx.x;
    if (i < n) Ap[(size_t)(i >> 7) * 512 + (i & 127)] = __float2bfloat16(x[i]);
}

// ---------------- BT for ALL layers: BT[l][j][k], B = [W_self; W3[0..2]] ----------
__global__ void k_wcat(const float* __restrict__ Wself,  // [L,128,128] (k,j)
                       const float* __restrict__ W3,     // [L,3,128,128]
                       __hip_bfloat16* __restrict__ BT,  // [L][128][512]
                       int L){
    int i = blockIdx.x * 256 + threadIdx.x;
    if (i >= L * 65536) return;
    int l = i >> 16, r = i & 65535;
    int j = r >> 9, k = r & 511;
    float v;
    if (k < 128) v = Wself[l * 16384 + k * 128 + j];
    else {
        int c = (k >> 7) - 1, kk = k & 127;
        v = W3[l * 49152 + (c * 128 + kk) * 128 + j];
    }
    BT[i] = __float2bfloat16(v);
}

// ---------------- aggregate: Y_c[t] = dt_c * sum_e nv_c[e] * x[src[e]] ----------
__global__ __launch_bounds__(256) void k_msg(
        __hip_bfloat16* __restrict__ Ap,   // [N,512]: cols 0..127 = x (read), 128..511 = Y (write)
        const uint2* __restrict__ nv,      // [E] packed, CSR order (this layer)
        const int* __restrict__ rs,        // [N+1]
        const float* __restrict__ dinv,    // [N,3] (this layer)
        int N){
    int w = threadIdx.x >> 6, lane = threadIdx.x & 63;
    int t = blockIdx.x * 4 + w;
    if (t >= N) return;
    float ax0 = 0.f, ay0 = 0.f, ax1 = 0.f, ay1 = 0.f, ax2 = 0.f, ay2 = 0.f;
    int beg = rs[t], end = rs[t + 1];
    int i = beg;
    for (; i + 8 <= end; i += 8){
        uint2 m[8];
        #pragma unroll
        for (int u = 0; u < 8; ++u) m[u] = nv[i + u];
        float2 f[8];
        #pragma unroll
        for (int u = 0; u < 8; ++u){
            const __hip_bfloat162* p =
                (const __hip_bfloat162*)(Ap + (size_t)(m[u].x & 0xFFFFu) * 512);
            f[u] = __bfloat1622float2(p[lane]);
        }
        #pragma unroll
        for (int u = 0; u < 8; ++u){
            float n0 = bf16hi_to_f32(m[u].x & 0xFFFF0000u);
            float n1 = bf16hi_to_f32(m[u].y << 16);
            float n2 = bf16hi_to_f32(m[u].y & 0xFFFF0000u);
            ax0 += n0 * f[u].x; ay0 += n0 * f[u].y;
            ax1 += n1 * f[u].x; ay1 += n1 * f[u].y;
            ax2 += n2 * f[u].x; ay2 += n2 * f[u].y;
        }
    }
    for (; i < end; ++i){
        uint2 m = nv[i];
        const __hip_bfloat162* p =
            (const __hip_bfloat162*)(Ap + (size_t)(m.x & 0xFFFFu) * 512);
        float2 fv = __bfloat1622float2(p[lane]);
        float n0 = bf16hi_to_f32(m.x & 0xFFFF0000u);
        float n1 = bf16hi_to_f32(m.y << 16);
        float n2 = bf16hi_to_f32(m.y & 0xFFFF0000u);
        ax0 += n0 * fv.x; ay0 += n0 * fv.y;
        ax1 += n1 * fv.x; ay1 += n1 * fv.y;
        ax2 += n2 * fv.x; ay2 += n2 * fv.y;
    }
    float dt0 = dinv[3 * t], dt1 = dinv[3 * t + 1], dt2 = dinv[3 * t + 2];
    __hip_bfloat162* yo = (__hip_bfloat162*)(Ap + (size_t)t * 512 + 128) + lane;
    float2 r0 = {dt0 * ax0, dt0 * ay0};
    float2 r1 = {dt1 * ax1, dt1 * ay1};
    float2 r2 = {dt2 * ax2, dt2 * ay2};
    yo[0]   = __float22bfloat162_rn(r0);
    yo[64]  = __float22bfloat162_rn(r1);
    yo[128] = __float22bfloat162_rn(r2);
}

// ---------------- GEMM: out[M,128] = A'[M,512] @ B[512,128] + bias ----------
__global__ __launch_bounds__(256) void k_gemm(
        const __hip_bfloat16* __restrict__ A,   // [M,512] bf16
        const __hip_bfloat16* __restrict__ BT,  // [128,512] bf16 ([j][k])
        const float* __restrict__ bias,         // [128] fp32
        float* __restrict__ outbuf,             // [M,128]
        int M){
    __shared__ __hip_bfloat16 As[128 * 128];
    __shared__ __hip_bfloat16 Bs[128 * 128];
    const int tid = threadIdx.x;
    const int row0 = blockIdx.x * 128;
    const int w = tid >> 6, lane = tid & 63;
    const int wm = (w & 1) * 64, wn = (w >> 1) * 64;
    const int lm = lane & 15, lq = lane >> 4;

    f32x4 acc[4][4];
    #pragma unroll
    for (int mt = 0; mt < 4; ++mt)
        #pragma unroll
        for (int nt = 0; nt < 4; ++nt)
            acc[mt][nt] = {0.f, 0.f, 0.f, 0.f};

    for (int kt = 0; kt < 4; ++kt){
        #pragma unroll
        for (int it = 0; it < 8; ++it){
            int v = it * 256 + tid;
            int r = v >> 4, c = v & 15;
            int soff = r * 128 + ((c ^ (r & 15)) << 3);
            int4 av = {0, 0, 0, 0};
            if (row0 + r < M)
                av = *(const int4*)(A + (size_t)(row0 + r) * 512 + kt * 128 + (c << 3));
            *(int4*)(&As[soff]) = av;
            int4 bv = *(const int4*)(BT + (size_t)r * 512 + kt * 128 + (c << 3));
            *(int4*)(&Bs[soff]) = bv;
        }
        __syncthreads();

        #pragma unroll
        for (int kk = 0; kk < 4; ++kk){
            int kc = kk * 4 + lq;
            bf16x8 a[4], b[4];
            #pragma unroll
            for (int mt = 0; mt < 4; ++mt){
                int r = wm + mt * 16 + lm;
                a[mt] = *(const bf16x8*)(&As[r * 128 + ((kc ^ (r & 15)) << 3)]);
            }
            #pragma unroll
            for (int nt = 0; nt < 4; ++nt){
                int r = wn + nt * 16 + lm;
                b[nt] = *(const bf16x8*)(&Bs[r * 128 + ((kc ^ (r & 15)) << 3)]);
            }
            #pragma unroll
            for (int mt = 0; mt < 4; ++mt)
                #pragma unroll
                for (int nt = 0; nt < 4; ++nt)
                    acc[mt][nt] = __builtin_amdgcn_mfma_f32_16x16x32_bf16(
                        a[mt], b[nt], acc[mt][nt], 0, 0, 0);
        }
        __syncthreads();
    }

    #pragma unroll
    for (int mt = 0; mt < 4; ++mt){
        #pragma unroll
        for (int nt = 0; nt < 4; ++nt){
            int col = wn + nt * 16 + lm;
            #pragma unroll
            for (int r = 0; r < 4; ++r){
                int row = row0 + wm + mt * 16 + lq * 4 + r;
                if (row < M)
                    outbuf[(size_t)row * 128 + col] = acc[mt][nt][r] + bias[col];
            }
        }
    }
}

// ---------------- LayerNorm + ReLU -> bf16 into A'[:,0:128] ----------------
__global__ __launch_bounds__(256) void k_ln(
        const float* __restrict__ outbuf,
        const float* __restrict__ g,
        const float* __restrict__ b,
        __hip_bfloat16* __restrict__ Ap, int N){
    int w = threadIdx.x >> 6, lane = threadIdx.x & 63;
    int t = blockIdx.x * 4 + w;
    if (t >= N) return;
    const float* row = outbuf + (size_t)t * 128;
    float x0 = row[2 * lane], x1 = row[2 * lane + 1];
    float s = x0 + x1;
    #pragma unroll
    for (int off = 32; off; off >>= 1) s += __shfl_xor(s, off);
    float mu = s * (1.0f / 128.0f);
    float d0 = x0 - mu, d1 = x1 - mu;
    float ss = d0 * d0 + d1 * d1;
    #pragma unroll
    for (int off = 32; off; off >>= 1) ss += __shfl_xor(ss, off);
    float r = rsqrtf(ss * (1.0f / 128.0f) + 1e-5f);
    float y0 = fmaxf(d0 * r * g[2 * lane]     + b[2 * lane],     0.0f);
    float y1 = fmaxf(d1 * r * g[2 * lane + 1] + b[2 * lane + 1], 0.0f);
    float2 y = {y0, y1};
    *((__hip_bfloat162*)(Ap + (size_t)t * 512) + lane) = __float22bfloat162_rn(y);
}

extern "C" void kernel_launch(void* const* d_in, const int* in_sizes, int n_in,
                              void* d_out, int out_size, void* d_ws, size_t ws_size,
                              hipStream_t stream) {
    const float* x     = (const float*)d_in[0];
    const int*   ei    = (const int*)d_in[1];
    const float* asp   = (const float*)d_in[2];
    const float* actx  = (const float*)d_in[3];
    const float* alat  = (const float*)d_in[4];
    const float* wsp   = (const float*)d_in[5];
    const float* wctx  = (const float*)d_in[6];
    const float* wlat  = (const float*)d_in[7];
    const float* W3    = (const float*)d_in[8];
    const float* Wself = (const float*)d_in[9];
    const float* bias  = (const float*)d_in[10];
    const float* dpow  = (const float*)d_in[11];
    const float* lng   = (const float*)d_in[12];
    const float* lnb   = (const float*)d_in[13];

    const int N = in_sizes[0] / 128;
    const int E = in_sizes[1] / 2;
    const int L = in_sizes[8] / (3 * 128 * 128);
    const int NB = cdiv(N, BK);           // buckets of 128 targets (N <= 65536 -> NB <= 512)
    const int* src = ei;
    const int* tgt = ei + E;

    // workspace carve (256B-aligned)
    char* p = (char*)d_ws;
    auto alloc = [&](size_t bytes) -> void* {
        void* r = (void*)p;
        p += (bytes + 255) & ~(size_t)255;
        return r;
    };
    int*   rs       = (int*)  alloc((size_t)(N + 1) * 4);
    int*   gcnt     = (int*)  alloc(1024 * 4);
    int*   bbase    = (int*)  alloc(1025 * 4);
    int*   gcur     = (int*)  alloc(1024 * 4);
    uint2* effo     = (uint2*)alloc((size_t)E * 8);
    uint2* nv       = (uint2*)alloc((size_t)L * E * 8);
    float* dinv_all = (float*)alloc((size_t)L * N * 3 * 4);
    float* outbuf   = (float*)alloc((size_t)N * 128 * 4);
    __hip_bfloat16* Ap = (__hip_bfloat16*)alloc((size_t)N * 512 * 2);  // [x|Y0|Y1|Y2]
    __hip_bfloat16* BT = (__hip_bfloat16*)alloc((size_t)L * 128 * 512 * 2);
    uint4* binned = (uint4*)nv;  // aliased: binned (E*16B) dead before nv (L*E*8B) written

    // ---- prep: bucketed counting-sort CSR build (no scattered-line writebacks) ----
    hipMemsetAsync(gcnt, 0, 1024 * 4, stream);
    k_bcnt0 <<<cdiv(E, 4096), 256, 0, stream>>>(tgt, gcnt, E, NB);
    k_bscan <<<1, 256, 0, stream>>>(gcnt, bbase, gcur, rs, N, E);
    k_bin   <<<cdiv(E, 4096), 256, 0, stream>>>(src, tgt, asp, actx, alat, wsp, wctx, wlat,
                                                gcur, binned, E, NB);
    k_bucket<<<NB, 256, 0, stream>>>(binned, bbase, effo, rs, N);
    k_deg   <<<cdiv(N, 256), 256, 0, stream>>>(effo, rs, dpow, dinv_all, N, L);
    k_x2bf  <<<cdiv(N * 128, 256), 256, 0, stream>>>(x, Ap, N * 128);
    k_wcat  <<<cdiv(L * 65536, 256), 256, 0, stream>>>(Wself, W3, BT, L);
    k_normv <<<cdiv(L * E, 256), 256, 0, stream>>>(effo, dinv_all, nv, E, N, L);

    // ---- layers ----
    for (int l = 0; l < L; ++l){
        float* obuf = (l == L - 1) ? (float*)d_out : outbuf;
        const float* dinv_l = dinv_all + (size_t)l * N * 3;
        k_msg <<<cdiv(N, 4), 256, 0, stream>>>(Ap, nv + (size_t)l * E, rs, dinv_l, N);
        k_gemm<<<cdiv(N, 128), 256, 0, stream>>>(Ap, BT + (size_t)l * 65536,
                                                 bias + l * 128, obuf, N);
        if (l < L - 1)
            k_ln<<<cdiv(N, 4), 256, 0, stream>>>(obuf, lng, lnb, Ap, N);
    }
}

// Round 10
// 363.762 us; speedup vs baseline: 2.3710x; 1.0202x over previous
//
#include <hip/hip_runtime.h>
#include <hip/hip_bf16.h>

typedef short bf16x8 __attribute__((ext_vector_type(8)));
typedef float f32x4 __attribute__((ext_vector_type(4)));

#define BSH 7            // 128 targets per bucket
#define BK  (1 << BSH)

static inline int cdiv(int a, int b){ return (a + b - 1) / b; }

__device__ __forceinline__ unsigned pack_bf16_hi(float v){
    return ((unsigned)__bfloat16_as_ushort(__float2bfloat16(v))) << 16;
}
__device__ __forceinline__ float bf16hi_to_f32(unsigned bits_hi16){
    return __uint_as_float(bits_hi16);  // bf16 bits already in [31:16]
}

// ---------- pass 0: global bucket histogram (LDS-privatized) ----------
__global__ __launch_bounds__(256) void k_bcnt0(const int* __restrict__ tgt,
                                               int* __restrict__ gcnt, int E, int NB){
    __shared__ int lh[1024];
    int tid = threadIdx.x;
    for (int b = tid; b < 1024; b += 256) lh[b] = 0;
    __syncthreads();
    int c0 = blockIdx.x * 4096;
    #pragma unroll
    for (int u = 0; u < 16; ++u){
        int e = c0 + u * 256 + tid;
        if (e < E) atomicAdd(&lh[tgt[e] >> BSH], 1);
    }
    __syncthreads();
    for (int b = tid; b < NB; b += 256){
        int c = lh[b];
        if (c) atomicAdd(&gcnt[b], c);
    }
}

// ---------- pass 0.5: scan bucket counts -> bases (= CSR bucket bases) ----------
__global__ __launch_bounds__(256) void k_bscan(const int* __restrict__ gcnt,
                                               int* __restrict__ bbase,
                                               int* __restrict__ gcur,
                                               int* __restrict__ rs,
                                               int N, int E){
    __shared__ int sc[256];
    int tid = threadIdx.x;
    int b0 = tid * 4;
    int v0 = gcnt[b0], v1 = gcnt[b0 + 1], v2 = gcnt[b0 + 2], v3 = gcnt[b0 + 3];
    int t3 = v0 + v1 + v2 + v3;
    sc[tid] = t3;
    __syncthreads();
    for (int off = 1; off < 256; off <<= 1){
        int x = (tid >= off) ? sc[tid - off] : 0;
        __syncthreads();
        sc[tid] += x;
        __syncthreads();
    }
    int ex = sc[tid] - t3;
    bbase[b0]     = ex;
    bbase[b0 + 1] = ex + v0;
    bbase[b0 + 2] = ex + v0 + v1;
    bbase[b0 + 3] = ex + v0 + v1 + v2;
    gcur[b0] = bbase[b0]; gcur[b0 + 1] = bbase[b0 + 1];
    gcur[b0 + 2] = bbase[b0 + 2]; gcur[b0 + 3] = bbase[b0 + 3];
    if (tid == 255) bbase[1024] = sc[255];   // == E
    if (tid == 0)   rs[N] = E;
}

// ---------- pass 1: bin edges into bucket-contiguous regions via LDS staging ----------
__global__ __launch_bounds__(256) void k_bin(
        const int* __restrict__ src, const int* __restrict__ tgt,
        const float* __restrict__ asp, const float* __restrict__ actx,
        const float* __restrict__ alat, const float* __restrict__ wsp,
        const float* __restrict__ wctx, const float* __restrict__ wlat,
        int* __restrict__ gcur, uint4* __restrict__ binned, int E, int NB){
    __shared__ int lh[1024], lo[1024], lc[1024], gb[1024], tsum[256];
    __shared__ unsigned sx[4096], sy[4096];
    __shared__ int st[4096];
    int tid = threadIdx.x;
    int c0 = blockIdx.x * 4096;
    int cnt = E - c0; if (cnt > 4096) cnt = 4096;
    for (int b = tid; b < 1024; b += 256){ lh[b] = 0; lc[b] = 0; }
    __syncthreads();
    #pragma unroll
    for (int u = 0; u < 16; ++u){
        int e = c0 + u * 256 + tid;
        if (e < E) atomicAdd(&lh[tgt[e] >> BSH], 1);
    }
    __syncthreads();
    int b4 = tid * 4;
    int v0 = lh[b4], v1 = lh[b4 + 1], v2 = lh[b4 + 2], v3 = lh[b4 + 3];
    int t3 = v0 + v1 + v2 + v3;
    tsum[tid] = t3;
    __syncthreads();
    for (int off = 1; off < 256; off <<= 1){
        int x = (tid >= off) ? tsum[tid - off] : 0;
        __syncthreads();
        tsum[tid] += x;
        __syncthreads();
    }
    int ex = tsum[tid] - t3;
    lo[b4] = ex; lo[b4 + 1] = ex + v0; lo[b4 + 2] = ex + v0 + v1; lo[b4 + 3] = ex + v0 + v1 + v2;
    for (int b = tid; b < NB; b += 256){
        int c = lh[b];
        gb[b] = c ? atomicAdd(&gcur[b], c) : 0;
    }
    __syncthreads();
    #pragma unroll
    for (int u = 0; u < 16; ++u){
        int e = c0 + u * 256 + tid;
        if (e < E){
            int t = tgt[e];
            int b = t >> BSH;
            int p = lo[b] + atomicAdd(&lc[b], 1);
            sx[p] = (unsigned)src[e] | pack_bf16_hi(asp[e] * wsp[e]);
            sy[p] = (pack_bf16_hi(actx[e] * wctx[e]) >> 16) | pack_bf16_hi(alat[e] * wlat[e]);
            st[p] = t;
        }
    }
    __syncthreads();
    for (int i = tid; i < cnt; i += 256){
        int t = st[i];
        int b = t >> BSH;
        int g = gb[b] + (i - lo[b]);
        uint4 o = {sx[i], sy[i], (unsigned)t, 0u};
        binned[g] = o;
    }
}

// ---------- pass 2: per-bucket CSR finalize (writes rs + final effo) ----------
__global__ __launch_bounds__(256) void k_bucket(
        const uint4* __restrict__ binned, const int* __restrict__ bbase,
        uint2* __restrict__ effo, int* __restrict__ rs, int N){
    __shared__ int th[128], sc2[128], cur[128];
    int tid = threadIdx.x;
    int b = blockIdx.x;
    int t0 = b << BSH;
    int ebeg = bbase[b], eend = bbase[b + 1];
    if (tid < 128) th[tid] = 0;
    __syncthreads();
    for (int i = ebeg + tid; i < eend; i += 256)
        atomicAdd(&th[(int)binned[i].z - t0], 1);
    __syncthreads();
    int v = (tid < 128) ? th[tid] : 0;
    if (tid < 128) sc2[tid] = v;
    __syncthreads();
    for (int off = 1; off < 128; off <<= 1){
        int x = (tid >= off && tid < 128) ? sc2[tid - off] : 0;
        __syncthreads();
        if (tid < 128) sc2[tid] += x;
        __syncthreads();
    }
    if (tid < 128){
        int exv = sc2[tid] - v;
        cur[tid] = exv;
        int t = t0 + tid;
        if (t < N) rs[t] = ebeg + exv;
    }
    __syncthreads();
    for (int i = ebeg + tid; i < eend; i += 256){
        uint4 r = binned[i];
        int loc = (int)r.z - t0;
        int p = atomicAdd(&cur[loc], 1);
        uint2 o = {r.x, r.y};
        effo[ebeg + p] = o;
    }
}

// ---------------- deg: thread-per-node segment sum; dinv for all layers ----------
__global__ __launch_bounds__(256) void k_deg(
        const uint2* __restrict__ effo, const int* __restrict__ rs,
        const float* __restrict__ dp,        // deg_power [L*3] fp32
        float* __restrict__ dinv_all,        // [L][N][3]
        int N, int L){
    int n = blockIdx.x * 256 + threadIdx.x;
    if (n >= N) return;
    int beg = rs[n], end = rs[n + 1];
    float s0 = 0.f, s1 = 0.f, s2 = 0.f;
    for (int i = beg; i < end; ++i){
        uint2 v = effo[i];
        s0 += bf16hi_to_f32(v.x & 0xFFFF0000u);
        s1 += bf16hi_to_f32(v.y << 16);
        s2 += bf16hi_to_f32(v.y & 0xFFFF0000u);
    }
    float d0 = fmaxf(1.f + s0, 1e-6f);
    float d1 = fmaxf(1.f + s1, 1e-6f);
    float d2 = fmaxf(1.f + s2, 1e-6f);
    for (int l = 0; l < L; ++l){
        size_t base = ((size_t)l * N + n) * 3;
        dinv_all[base + 0] = powf(d0, dp[l * 3 + 0]);
        dinv_all[base + 1] = powf(d1, dp[l * 3 + 1]);
        dinv_all[base + 2] = powf(d2, dp[l * 3 + 2]);
    }
}

// ---------------- nv for ALL layers: nv[l*E+e] = {src, eff_c * dinv_c[l][src]} ----
__global__ void k_normv(const uint2* __restrict__ effo,
                        const float* __restrict__ dinv_all,  // [L][N][3]
                        uint2* __restrict__ nv, int E, int N, int L){
    int i = blockIdx.x * 256 + threadIdx.x;
    if (i >= L * E) return;
    int l = i / E;
    int e = i - l * E;
    const float* dinv = dinv_all + (size_t)l * N * 3;
    uint2 v = effo[e];
    unsigned s = v.x & 0xFFFFu;
    float e0 = bf16hi_to_f32(v.x & 0xFFFF0000u);
    float e1 = bf16hi_to_f32(v.y << 16);
    float e2 = bf16hi_to_f32(v.y & 0xFFFF0000u);
    float n0 = e0 * dinv[3 * s + 0];
    float n1 = e1 * dinv[3 * s + 1];
    float n2 = e2 * dinv[3 * s + 2];
    uint2 o;
    o.x = s | pack_bf16_hi(n0);
    o.y = (pack_bf16_hi(n1) >> 16) | pack_bf16_hi(n2);
    nv[i] = o;
}

// ---------------- x (fp32) -> A'[:,0:128] (bf16, row stride 512) ----------------
__global__ void k_x2bf(const float* __restrict__ x, __hip_bfloat16* __restrict__ Ap, int n){
    int i = blockIdx.x * 256 + threadIdx.x;
    if (i < n) Ap[(size_t)(i >> 7) * 512 + (i & 127)] = __float2bfloat16(x[i]);
}

// ---------------- BT for ALL layers: BT[l][j][k], B = [W_self; W3[0..2]] ----------
__global__ void k_wcat(const float* __restrict__ Wself,  // [L,128,128] (k,j)
                       const float* __restrict__ W3,     // [L,3,128,128]
                       __hip_bfloat16* __restrict__ BT,  // [L][128][512]
                       int L){
    int i = blockIdx.x * 256 + threadIdx.x;
    if (i >= L * 65536) return;
    int l = i >> 16, r = i & 65535;
    int j = r >> 9, k = r & 511;
    float v;
    if (k < 128) v = Wself[l * 16384 + k * 128 + j];
    else {
        int c = (k >> 7) - 1, kk = k & 127;
        v = W3[l * 49152 + (c * 128 + kk) * 128 + j];
    }
    BT[i] = __float2bfloat16(v);
}

// ---------------- aggregate: Y_c[t] = dt_c * sum_e nv_c[e] * x[src[e]] ----------
// unroll 16 / 4 / 1 tiers for gather MLP
__global__ __launch_bounds__(256) void k_msg(
        __hip_bfloat16* __restrict__ Ap,   // [N,512]: cols 0..127 = x (read), 128..511 = Y (write)
        const uint2* __restrict__ nv,      // [E] packed, CSR order (this layer)
        const int* __restrict__ rs,        // [N+1]
        const float* __restrict__ dinv,    // [N,3] (this layer)
        int N){
    int w = threadIdx.x >> 6, lane = threadIdx.x & 63;
    int t = blockIdx.x * 4 + w;
    if (t >= N) return;
    float ax0 = 0.f, ay0 = 0.f, ax1 = 0.f, ay1 = 0.f, ax2 = 0.f, ay2 = 0.f;
    int beg = rs[t], end = rs[t + 1];
    int i = beg;
    for (; i + 16 <= end; i += 16){
        uint2 m[16];
        #pragma unroll
        for (int u = 0; u < 16; ++u) m[u] = nv[i + u];
        float2 f[16];
        #pragma unroll
        for (int u = 0; u < 16; ++u){
            const __hip_bfloat162* p =
                (const __hip_bfloat162*)(Ap + (size_t)(m[u].x & 0xFFFFu) * 512);
            f[u] = __bfloat1622float2(p[lane]);
        }
        #pragma unroll
        for (int u = 0; u < 16; ++u){
            float n0 = bf16hi_to_f32(m[u].x & 0xFFFF0000u);
            float n1 = bf16hi_to_f32(m[u].y << 16);
            float n2 = bf16hi_to_f32(m[u].y & 0xFFFF0000u);
            ax0 += n0 * f[u].x; ay0 += n0 * f[u].y;
            ax1 += n1 * f[u].x; ay1 += n1 * f[u].y;
            ax2 += n2 * f[u].x; ay2 += n2 * f[u].y;
        }
    }
    for (; i + 4 <= end; i += 4){
        uint2 m[4];
        #pragma unroll
        for (int u = 0; u < 4; ++u) m[u] = nv[i + u];
        float2 f[4];
        #pragma unroll
        for (int u = 0; u < 4; ++u){
            const __hip_bfloat162* p =
                (const __hip_bfloat162*)(Ap + (size_t)(m[u].x & 0xFFFFu) * 512);
            f[u] = __bfloat1622float2(p[lane]);
        }
        #pragma unroll
        for (int u = 0; u < 4; ++u){
            float n0 = bf16hi_to_f32(m[u].x & 0xFFFF0000u);
            float n1 = bf16hi_to_f32(m[u].y << 16);
            float n2 = bf16hi_to_f32(m[u].y & 0xFFFF0000u);
            ax0 += n0 * f[u].x; ay0 += n0 * f[u].y;
            ax1 += n1 * f[u].x; ay1 += n1 * f[u].y;
            ax2 += n2 * f[u].x; ay2 += n2 * f[u].y;
        }
    }
    for (; i < end; ++i){
        uint2 m = nv[i];
        const __hip_bfloat162* p =
            (const __hip_bfloat162*)(Ap + (size_t)(m.x & 0xFFFFu) * 512);
        float2 fv = __bfloat1622float2(p[lane]);
        float n0 = bf16hi_to_f32(m.x & 0xFFFF0000u);
        float n1 = bf16hi_to_f32(m.y << 16);
        float n2 = bf16hi_to_f32(m.y & 0xFFFF0000u);
        ax0 += n0 * fv.x; ay0 += n0 * fv.y;
        ax1 += n1 * fv.x; ay1 += n1 * fv.y;
        ax2 += n2 * fv.x; ay2 += n2 * fv.y;
    }
    float dt0 = dinv[3 * t], dt1 = dinv[3 * t + 1], dt2 = dinv[3 * t + 2];
    __hip_bfloat162* yo = (__hip_bfloat162*)(Ap + (size_t)t * 512 + 128) + lane;
    float2 r0 = {dt0 * ax0, dt0 * ay0};
    float2 r1 = {dt1 * ax1, dt1 * ay1};
    float2 r2 = {dt2 * ax2, dt2 * ay2};
    yo[0]   = __float22bfloat162_rn(r0);
    yo[64]  = __float22bfloat162_rn(r1);
    yo[128] = __float22bfloat162_rn(r2);
}

// ---------------- GEMM: out = A'[M,512] @ B[512,128] + bias; optional fused LN+ReLU
// doLN==0: write fp32 out+bias to outbuf.  doLN==1: LN+ReLU -> bf16 into Ap[:,0:128].
__global__ __launch_bounds__(256) void k_gemm(
        const __hip_bfloat16* __restrict__ A,   // [M,512] bf16
        const __hip_bfloat16* __restrict__ BT,  // [128,512] bf16 ([j][k])
        const float* __restrict__ bias,         // [128] fp32
        float* __restrict__ outbuf,             // [M,128] (doLN==0)
        int M, int doLN,
        const float* __restrict__ g, const float* __restrict__ b,
        __hip_bfloat16* __restrict__ Ap){       // (doLN==1)
    __shared__ __hip_bfloat16 As[128 * 128];
    __shared__ __hip_bfloat16 Bs[128 * 128];
    const int tid = threadIdx.x;
    const int row0 = blockIdx.x * 128;
    const int w = tid >> 6, lane = tid & 63;
    const int wm = (w & 1) * 64, wn = (w >> 1) * 64;
    const int lm = lane & 15, lq = lane >> 4;

    f32x4 acc[4][4];
    #pragma unroll
    for (int mt = 0; mt < 4; ++mt)
        #pragma unroll
        for (int nt = 0; nt < 4; ++nt)
            acc[mt][nt] = {0.f, 0.f, 0.f, 0.f};

    for (int kt = 0; kt < 4; ++kt){
        #pragma unroll
        for (int it = 0; it < 8; ++it){
            int v = it * 256 + tid;
            int r = v >> 4, c = v & 15;
            int soff = r * 128 + ((c ^ (r & 15)) << 3);
            int4 av = {0, 0, 0, 0};
            if (row0 + r < M)
                av = *(const int4*)(A + (size_t)(row0 + r) * 512 + kt * 128 + (c << 3));
            *(int4*)(&As[soff]) = av;
            int4 bv = *(const int4*)(BT + (size_t)r * 512 + kt * 128 + (c << 3));
            *(int4*)(&Bs[soff]) = bv;
        }
        __syncthreads();

        #pragma unroll
        for (int kk = 0; kk < 4; ++kk){
            int kc = kk * 4 + lq;
            bf16x8 a[4], b2[4];
            #pragma unroll
            for (int mt = 0; mt < 4; ++mt){
                int r = wm + mt * 16 + lm;
                a[mt] = *(const bf16x8*)(&As[r * 128 + ((kc ^ (r & 15)) << 3)]);
            }
            #pragma unroll
            for (int nt = 0; nt < 4; ++nt){
                int r = wn + nt * 16 + lm;
                b2[nt] = *(const bf16x8*)(&Bs[r * 128 + ((kc ^ (r & 15)) << 3)]);
            }
            #pragma unroll
            for (int mt = 0; mt < 4; ++mt)
                #pragma unroll
                for (int nt = 0; nt < 4; ++nt)
                    acc[mt][nt] = __builtin_amdgcn_mfma_f32_16x16x32_bf16(
                        a[mt], b2[nt], acc[mt][nt], 0, 0, 0);
        }
        __syncthreads();
    }

    if (!doLN){
        #pragma unroll
        for (int mt = 0; mt < 4; ++mt){
            #pragma unroll
            for (int nt = 0; nt < 4; ++nt){
                int col = wn + nt * 16 + lm;
                #pragma unroll
                for (int r = 0; r < 4; ++r){
                    int row = row0 + wm + mt * 16 + lq * 4 + r;
                    if (row < M)
                        outbuf[(size_t)row * 128 + col] = acc[mt][nt][r] + bias[col];
                }
            }
        }
    } else {
        // fused LN+ReLU epilogue. Reuse As for partial sums, Bs for mu/scale.
        float* S1 = (float*)As;          // [128][32] sum partials
        float* S2 = S1 + 4096;           // [128][32] sumsq partials
        float* MS = (float*)Bs;          // mu[128], sc[128]
        const int half = wn >> 6;        // 0 or 1
        const int slot = half * 16 + lm;
        float bv[4];
        #pragma unroll
        for (int nt = 0; nt < 4; ++nt) bv[nt] = bias[wn + nt * 16 + lm];
        #pragma unroll
        for (int mt = 0; mt < 4; ++mt){
            #pragma unroll
            for (int r = 0; r < 4; ++r){
                int rl = wm + mt * 16 + lq * 4 + r;
                float ps = 0.f, pq = 0.f;
                #pragma unroll
                for (int nt = 0; nt < 4; ++nt){
                    float v = acc[mt][nt][r] + bv[nt];
                    ps += v; pq += v * v;
                }
                S1[rl * 32 + slot] = ps;
                S2[rl * 32 + slot] = pq;
            }
        }
        __syncthreads();
        if (tid < 128){
            float s = 0.f, sq = 0.f;
            #pragma unroll
            for (int j = 0; j < 32; ++j){
                s  += S1[tid * 32 + j];
                sq += S2[tid * 32 + j];
            }
            float mu = s * (1.0f / 128.0f);
            float var = sq * (1.0f / 128.0f) - mu * mu;
            MS[tid] = mu;
            MS[128 + tid] = rsqrtf(var + 1e-5f);
        }
        __syncthreads();
        float gv[4], bbv[4];
        #pragma unroll
        for (int nt = 0; nt < 4; ++nt){
            int col = wn + nt * 16 + lm;
            gv[nt] = g[col]; bbv[nt] = b[col];
        }
        #pragma unroll
        for (int mt = 0; mt < 4; ++mt){
            #pragma unroll
            for (int r = 0; r < 4; ++r){
                int rl = wm + mt * 16 + lq * 4 + r;
                int row = row0 + rl;
                if (row < M){
                    float mu = MS[rl], sc = MS[128 + rl];
                    #pragma unroll
                    for (int nt = 0; nt < 4; ++nt){
                        int col = wn + nt * 16 + lm;
                        float v = acc[mt][nt][r] + bv[nt];
                        float y = fmaxf((v - mu) * sc * gv[nt] + bbv[nt], 0.0f);
                        Ap[(size_t)row * 512 + col] = __float2bfloat16(y);
                    }
                }
            }
        }
    }
}

extern "C" void kernel_launch(void* const* d_in, const int* in_sizes, int n_in,
                              void* d_out, int out_size, void* d_ws, size_t ws_size,
                              hipStream_t stream) {
    const float* x     = (const float*)d_in[0];
    const int*   ei    = (const int*)d_in[1];
    const float* asp   = (const float*)d_in[2];
    const float* actx  = (const float*)d_in[3];
    const float* alat  = (const float*)d_in[4];
    const float* wsp   = (const float*)d_in[5];
    const float* wctx  = (const float*)d_in[6];
    const float* wlat  = (const float*)d_in[7];
    const float* W3    = (const float*)d_in[8];
    const float* Wself = (const float*)d_in[9];
    const float* bias  = (const float*)d_in[10];
    const float* dpow  = (const float*)d_in[11];
    const float* lng   = (const float*)d_in[12];
    const float* lnb   = (const float*)d_in[13];

    const int N = in_sizes[0] / 128;
    const int E = in_sizes[1] / 2;
    const int L = in_sizes[8] / (3 * 128 * 128);
    const int NB = cdiv(N, BK);
    const int* src = ei;
    const int* tgt = ei + E;

    // workspace carve (256B-aligned)
    char* p = (char*)d_ws;
    auto alloc = [&](size_t bytes) -> void* {
        void* r = (void*)p;
        p += (bytes + 255) & ~(size_t)255;
        return r;
    };
    int*   rs       = (int*)  alloc((size_t)(N + 1) * 4);
    int*   gcnt     = (int*)  alloc(1024 * 4);
    int*   bbase    = (int*)  alloc(1025 * 4);
    int*   gcur     = (int*)  alloc(1024 * 4);
    uint2* effo     = (uint2*)alloc((size_t)E * 8);
    uint2* nv       = (uint2*)alloc((size_t)L * E * 8);
    float* dinv_all = (float*)alloc((size_t)L * N * 3 * 4);
    __hip_bfloat16* Ap = (__hip_bfloat16*)alloc((size_t)N * 512 * 2);  // [x|Y0|Y1|Y2]
    __hip_bfloat16* BT = (__hip_bfloat16*)alloc((size_t)L * 128 * 512 * 2);
    uint4* binned = (uint4*)nv;  // aliased: binned (E*16B) dead before nv (L*E*8B) written

    // ---- prep: bucketed counting-sort CSR build ----
    hipMemsetAsync(gcnt, 0, 1024 * 4, stream);
    k_bcnt0 <<<cdiv(E, 4096), 256, 0, stream>>>(tgt, gcnt, E, NB);
    k_bscan <<<1, 256, 0, stream>>>(gcnt, bbase, gcur, rs, N, E);
    k_bin   <<<cdiv(E, 4096), 256, 0, stream>>>(src, tgt, asp, actx, alat, wsp, wctx, wlat,
                                                gcur, binned, E, NB);
    k_bucket<<<NB, 256, 0, stream>>>(binned, bbase, effo, rs, N);
    k_deg   <<<cdiv(N, 256), 256, 0, stream>>>(effo, rs, dpow, dinv_all, N, L);
    k_x2bf  <<<cdiv(N * 128, 256), 256, 0, stream>>>(x, Ap, N * 128);
    k_wcat  <<<cdiv(L * 65536, 256), 256, 0, stream>>>(Wself, W3, BT, L);
    k_normv <<<cdiv(L * E, 256), 256, 0, stream>>>(effo, dinv_all, nv, E, N, L);

    // ---- layers ----
    for (int l = 0; l < L; ++l){
        int doLN = (l < L - 1) ? 1 : 0;
        const float* dinv_l = dinv_all + (size_t)l * N * 3;
        k_msg <<<cdiv(N, 4), 256, 0, stream>>>(Ap, nv + (size_t)l * E, rs, dinv_l, N);
        k_gemm<<<cdiv(N, 128), 256, 0, stream>>>(Ap, BT + (size_t)l * 65536,
                                                 bias + l * 128, (float*)d_out, N,
                                                 doLN, lng, lnb, Ap);
    }
}

// Round 11
// 349.369 us; speedup vs baseline: 2.4687x; 1.0412x over previous
//
#include <hip/hip_runtime.h>
#include <hip/hip_bf16.h>

typedef short bf16x8 __attribute__((ext_vector_type(8)));
typedef float f32x4 __attribute__((ext_vector_type(4)));

#define BSH 7            // 128 targets per bucket
#define BK  (1 << BSH)

static inline int cdiv(int a, int b){ return (a + b - 1) / b; }

__device__ __forceinline__ unsigned pack_bf16_hi(float v){
    return ((unsigned)__bfloat16_as_ushort(__float2bfloat16(v))) << 16;
}
__device__ __forceinline__ float bf16hi_to_f32(unsigned bits_hi16){
    return __uint_as_float(bits_hi16);  // bf16 bits already in [31:16]
}

// ---------- pass 0: global bucket histogram (LDS-privatized) ----------
__global__ __launch_bounds__(256) void k_bcnt0(const int* __restrict__ tgt,
                                               int* __restrict__ gcnt, int E, int NB){
    __shared__ int lh[1024];
    int tid = threadIdx.x;
    for (int b = tid; b < 1024; b += 256) lh[b] = 0;
    __syncthreads();
    int c0 = blockIdx.x * 4096;
    #pragma unroll
    for (int u = 0; u < 16; ++u){
        int e = c0 + u * 256 + tid;
        if (e < E) atomicAdd(&lh[tgt[e] >> BSH], 1);
    }
    __syncthreads();
    for (int b = tid; b < NB; b += 256){
        int c = lh[b];
        if (c) atomicAdd(&gcnt[b], c);
    }
}

// ---------- pass 0.5: scan bucket counts -> bases (= CSR bucket bases) ----------
__global__ __launch_bounds__(256) void k_bscan(const int* __restrict__ gcnt,
                                               int* __restrict__ bbase,
                                               int* __restrict__ gcur,
                                               int* __restrict__ rs,
                                               int N, int E){
    __shared__ int sc[256];
    int tid = threadIdx.x;
    int b0 = tid * 4;
    int v0 = gcnt[b0], v1 = gcnt[b0 + 1], v2 = gcnt[b0 + 2], v3 = gcnt[b0 + 3];
    int t3 = v0 + v1 + v2 + v3;
    sc[tid] = t3;
    __syncthreads();
    for (int off = 1; off < 256; off <<= 1){
        int x = (tid >= off) ? sc[tid - off] : 0;
        __syncthreads();
        sc[tid] += x;
        __syncthreads();
    }
    int ex = sc[tid] - t3;
    bbase[b0]     = ex;
    bbase[b0 + 1] = ex + v0;
    bbase[b0 + 2] = ex + v0 + v1;
    bbase[b0 + 3] = ex + v0 + v1 + v2;
    gcur[b0] = bbase[b0]; gcur[b0 + 1] = bbase[b0 + 1];
    gcur[b0 + 2] = bbase[b0 + 2]; gcur[b0 + 3] = bbase[b0 + 3];
    if (tid == 255) bbase[1024] = sc[255];   // == E
    if (tid == 0)   rs[N] = E;
}

// ---------- pass 1: bin edges into bucket-contiguous regions (direct write) ----------
// (LDS payload staging removed: it only reordered within ~160B per-bucket runs —
//  no writeback benefit; cost 48KB LDS + 2 barriers.)
__global__ __launch_bounds__(256) void k_bin(
        const int* __restrict__ src, const int* __restrict__ tgt,
        const float* __restrict__ asp, const float* __restrict__ actx,
        const float* __restrict__ alat, const float* __restrict__ wsp,
        const float* __restrict__ wctx, const float* __restrict__ wlat,
        int* __restrict__ gcur, uint4* __restrict__ binned, int E, int NB){
    __shared__ int lh[1024], lc[1024], gb[1024];
    int tid = threadIdx.x;
    int c0 = blockIdx.x * 4096;
    for (int b = tid; b < 1024; b += 256){ lh[b] = 0; lc[b] = 0; }
    __syncthreads();
    #pragma unroll
    for (int u = 0; u < 16; ++u){
        int e = c0 + u * 256 + tid;
        if (e < E) atomicAdd(&lh[tgt[e] >> BSH], 1);
    }
    __syncthreads();
    for (int b = tid; b < NB; b += 256){
        int c = lh[b];
        gb[b] = c ? atomicAdd(&gcur[b], c) : 0;
    }
    __syncthreads();
    #pragma unroll
    for (int u = 0; u < 16; ++u){
        int e = c0 + u * 256 + tid;
        if (e < E){
            int t = tgt[e];
            int b = t >> BSH;
            int p = gb[b] + atomicAdd(&lc[b], 1);
            uint4 o;
            o.x = (unsigned)src[e] | pack_bf16_hi(asp[e] * wsp[e]);
            o.y = (pack_bf16_hi(actx[e] * wctx[e]) >> 16) | pack_bf16_hi(alat[e] * wlat[e]);
            o.z = (unsigned)t;
            o.w = 0u;
            binned[p] = o;
        }
    }
}

// ---------- pass 2: per-bucket CSR finalize (writes rs + final effo) ----------
__global__ __launch_bounds__(256) void k_bucket(
        const uint4* __restrict__ binned, const int* __restrict__ bbase,
        uint2* __restrict__ effo, int* __restrict__ rs, int N){
    __shared__ int th[128], sc2[128], cur[128];
    int tid = threadIdx.x;
    int b = blockIdx.x;
    int t0 = b << BSH;
    int ebeg = bbase[b], eend = bbase[b + 1];
    if (tid < 128) th[tid] = 0;
    __syncthreads();
    for (int i = ebeg + tid; i < eend; i += 256)
        atomicAdd(&th[(int)binned[i].z - t0], 1);
    __syncthreads();
    int v = (tid < 128) ? th[tid] : 0;
    if (tid < 128) sc2[tid] = v;
    __syncthreads();
    for (int off = 1; off < 128; off <<= 1){
        int x = (tid >= off && tid < 128) ? sc2[tid - off] : 0;
        __syncthreads();
        if (tid < 128) sc2[tid] += x;
        __syncthreads();
    }
    if (tid < 128){
        int exv = sc2[tid] - v;
        cur[tid] = exv;
        int t = t0 + tid;
        if (t < N) rs[t] = ebeg + exv;
    }
    __syncthreads();
    for (int i = ebeg + tid; i < eend; i += 256){
        uint4 r = binned[i];
        int loc = (int)r.z - t0;
        int p = atomicAdd(&cur[loc], 1);
        uint2 o = {r.x, r.y};
        effo[ebeg + p] = o;
    }
}

// ---------------- deg: thread-per-node segment sum; dinv for all layers ----------
__global__ __launch_bounds__(256) void k_deg(
        const uint2* __restrict__ effo, const int* __restrict__ rs,
        const float* __restrict__ dp,        // deg_power [L*3] fp32
        float* __restrict__ dinv_all,        // [L][N][3]
        int N, int L){
    int n = blockIdx.x * 256 + threadIdx.x;
    if (n >= N) return;
    int beg = rs[n], end = rs[n + 1];
    float s0 = 0.f, s1 = 0.f, s2 = 0.f;
    for (int i = beg; i < end; ++i){
        uint2 v = effo[i];
        s0 += bf16hi_to_f32(v.x & 0xFFFF0000u);
        s1 += bf16hi_to_f32(v.y << 16);
        s2 += bf16hi_to_f32(v.y & 0xFFFF0000u);
    }
    float d0 = fmaxf(1.f + s0, 1e-6f);
    float d1 = fmaxf(1.f + s1, 1e-6f);
    float d2 = fmaxf(1.f + s2, 1e-6f);
    for (int l = 0; l < L; ++l){
        size_t base = ((size_t)l * N + n) * 3;
        dinv_all[base + 0] = powf(d0, dp[l * 3 + 0]);
        dinv_all[base + 1] = powf(d1, dp[l * 3 + 1]);
        dinv_all[base + 2] = powf(d2, dp[l * 3 + 2]);
    }
}

// ---------------- nv for ALL layers: nv[l*E+e] = {src, eff_c * dinv_c[l][src]} ----
__global__ void k_normv(const uint2* __restrict__ effo,
                        const float* __restrict__ dinv_all,  // [L][N][3]
                        uint2* __restrict__ nv, int E, int N, int L){
    int i = blockIdx.x * 256 + threadIdx.x;
    if (i >= L * E) return;
    int l = i / E;
    int e = i - l * E;
    const float* dinv = dinv_all + (size_t)l * N * 3;
    uint2 v = effo[e];
    unsigned s = v.x & 0xFFFFu;
    float e0 = bf16hi_to_f32(v.x & 0xFFFF0000u);
    float e1 = bf16hi_to_f32(v.y << 16);
    float e2 = bf16hi_to_f32(v.y & 0xFFFF0000u);
    float n0 = e0 * dinv[3 * s + 0];
    float n1 = e1 * dinv[3 * s + 1];
    float n2 = e2 * dinv[3 * s + 2];
    uint2 o;
    o.x = s | pack_bf16_hi(n0);
    o.y = (pack_bf16_hi(n1) >> 16) | pack_bf16_hi(n2);
    nv[i] = o;
}

// ---------------- x (fp32) -> A'[:,0:128] (bf16, row stride 512) ----------------
__global__ void k_x2bf(const float* __restrict__ x, __hip_bfloat16* __restrict__ Ap, int n){
    int i = blockIdx.x * 256 + threadIdx.x;
    if (i < n) Ap[(size_t)(i >> 7) * 512 + (i & 127)] = __float2bfloat16(x[i]);
}

// ---------------- BT for ALL layers: BT[l][j][k], B = [W_self; W3[0..2]] ----------
__global__ void k_wcat(const float* __restrict__ Wself,  // [L,128,128] (k,j)
                       const float* __restrict__ W3,     // [L,3,128,128]
                       __hip_bfloat16* __restrict__ BT,  // [L][128][512]
                       int L){
    int i = blockIdx.x * 256 + threadIdx.x;
    if (i >= L * 65536) return;
    int l = i >> 16, r = i & 65535;
    int j = r >> 9, k = r & 511;
    float v;
    if (k < 128) v = Wself[l * 16384 + k * 128 + j];
    else {
        int c = (k >> 7) - 1, kk = k & 127;
        v = W3[l * 49152 + (c * 128 + kk) * 128 + j];
    }
    BT[i] = __float2bfloat16(v);
}

// ---------------- aggregate: Y_c[t] = dt_c * sum_e nv_c[e] * x[src[e]] ----------
// unroll 8 + scalar tail (VGPR ~28, occ ~59% — unroll 16 regressed: VGPR 48, occ 40%)
__global__ __launch_bounds__(256) void k_msg(
        __hip_bfloat16* __restrict__ Ap,   // [N,512]: cols 0..127 = x (read), 128..511 = Y (write)
        const uint2* __restrict__ nv,      // [E] packed, CSR order (this layer)
        const int* __restrict__ rs,        // [N+1]
        const float* __restrict__ dinv,    // [N,3] (this layer)
        int N){
    int w = threadIdx.x >> 6, lane = threadIdx.x & 63;
    int t = blockIdx.x * 4 + w;
    if (t >= N) return;
    float ax0 = 0.f, ay0 = 0.f, ax1 = 0.f, ay1 = 0.f, ax2 = 0.f, ay2 = 0.f;
    int beg = rs[t], end = rs[t + 1];
    int i = beg;
    for (; i + 8 <= end; i += 8){
        uint2 m[8];
        #pragma unroll
        for (int u = 0; u < 8; ++u) m[u] = nv[i + u];
        float2 f[8];
        #pragma unroll
        for (int u = 0; u < 8; ++u){
            const __hip_bfloat162* p =
                (const __hip_bfloat162*)(Ap + (size_t)(m[u].x & 0xFFFFu) * 512);
            f[u] = __bfloat1622float2(p[lane]);
        }
        #pragma unroll
        for (int u = 0; u < 8; ++u){
            float n0 = bf16hi_to_f32(m[u].x & 0xFFFF0000u);
            float n1 = bf16hi_to_f32(m[u].y << 16);
            float n2 = bf16hi_to_f32(m[u].y & 0xFFFF0000u);
            ax0 += n0 * f[u].x; ay0 += n0 * f[u].y;
            ax1 += n1 * f[u].x; ay1 += n1 * f[u].y;
            ax2 += n2 * f[u].x; ay2 += n2 * f[u].y;
        }
    }
    for (; i < end; ++i){
        uint2 m = nv[i];
        const __hip_bfloat162* p =
            (const __hip_bfloat162*)(Ap + (size_t)(m.x & 0xFFFFu) * 512);
        float2 fv = __bfloat1622float2(p[lane]);
        float n0 = bf16hi_to_f32(m.x & 0xFFFF0000u);
        float n1 = bf16hi_to_f32(m.y << 16);
        float n2 = bf16hi_to_f32(m.y & 0xFFFF0000u);
        ax0 += n0 * fv.x; ay0 += n0 * fv.y;
        ax1 += n1 * fv.x; ay1 += n1 * fv.y;
        ax2 += n2 * fv.x; ay2 += n2 * fv.y;
    }
    float dt0 = dinv[3 * t], dt1 = dinv[3 * t + 1], dt2 = dinv[3 * t + 2];
    __hip_bfloat162* yo = (__hip_bfloat162*)(Ap + (size_t)t * 512 + 128) + lane;
    float2 r0 = {dt0 * ax0, dt0 * ay0};
    float2 r1 = {dt1 * ax1, dt1 * ay1};
    float2 r2 = {dt2 * ax2, dt2 * ay2};
    yo[0]   = __float22bfloat162_rn(r0);
    yo[64]  = __float22bfloat162_rn(r1);
    yo[128] = __float22bfloat162_rn(r2);
}

// ---------------- GEMM: out = A'[M,512] @ B[512,128] + bias; optional fused LN+ReLU
__global__ __launch_bounds__(256) void k_gemm(
        const __hip_bfloat16* __restrict__ A,   // [M,512] bf16
        const __hip_bfloat16* __restrict__ BT,  // [128,512] bf16 ([j][k])
        const float* __restrict__ bias,         // [128] fp32
        float* __restrict__ outbuf,             // [M,128] (doLN==0)
        int M, int doLN,
        const float* __restrict__ g, const float* __restrict__ b,
        __hip_bfloat16* __restrict__ Ap){       // (doLN==1)
    __shared__ __hip_bfloat16 As[128 * 128];
    __shared__ __hip_bfloat16 Bs[128 * 128];
    const int tid = threadIdx.x;
    const int row0 = blockIdx.x * 128;
    const int w = tid >> 6, lane = tid & 63;
    const int wm = (w & 1) * 64, wn = (w >> 1) * 64;
    const int lm = lane & 15, lq = lane >> 4;

    f32x4 acc[4][4];
    #pragma unroll
    for (int mt = 0; mt < 4; ++mt)
        #pragma unroll
        for (int nt = 0; nt < 4; ++nt)
            acc[mt][nt] = {0.f, 0.f, 0.f, 0.f};

    for (int kt = 0; kt < 4; ++kt){
        #pragma unroll
        for (int it = 0; it < 8; ++it){
            int v = it * 256 + tid;
            int r = v >> 4, c = v & 15;
            int soff = r * 128 + ((c ^ (r & 15)) << 3);
            int4 av = {0, 0, 0, 0};
            if (row0 + r < M)
                av = *(const int4*)(A + (size_t)(row0 + r) * 512 + kt * 128 + (c << 3));
            *(int4*)(&As[soff]) = av;
            int4 bv = *(const int4*)(BT + (size_t)r * 512 + kt * 128 + (c << 3));
            *(int4*)(&Bs[soff]) = bv;
        }
        __syncthreads();

        #pragma unroll
        for (int kk = 0; kk < 4; ++kk){
            int kc = kk * 4 + lq;
            bf16x8 a[4], b2[4];
            #pragma unroll
            for (int mt = 0; mt < 4; ++mt){
                int r = wm + mt * 16 + lm;
                a[mt] = *(const bf16x8*)(&As[r * 128 + ((kc ^ (r & 15)) << 3)]);
            }
            #pragma unroll
            for (int nt = 0; nt < 4; ++nt){
                int r = wn + nt * 16 + lm;
                b2[nt] = *(const bf16x8*)(&Bs[r * 128 + ((kc ^ (r & 15)) << 3)]);
            }
            #pragma unroll
            for (int mt = 0; mt < 4; ++mt)
                #pragma unroll
                for (int nt = 0; nt < 4; ++nt)
                    acc[mt][nt] = __builtin_amdgcn_mfma_f32_16x16x32_bf16(
                        a[mt], b2[nt], acc[mt][nt], 0, 0, 0);
        }
        __syncthreads();
    }

    if (!doLN){
        #pragma unroll
        for (int mt = 0; mt < 4; ++mt){
            #pragma unroll
            for (int nt = 0; nt < 4; ++nt){
                int col = wn + nt * 16 + lm;
                #pragma unroll
                for (int r = 0; r < 4; ++r){
                    int row = row0 + wm + mt * 16 + lq * 4 + r;
                    if (row < M)
                        outbuf[(size_t)row * 128 + col] = acc[mt][nt][r] + bias[col];
                }
            }
        }
    } else {
        // fused LN+ReLU epilogue. Reuse As for partial sums, Bs for mu/scale.
        float* S1 = (float*)As;          // [128][32] sum partials
        float* S2 = S1 + 4096;           // [128][32] sumsq partials
        float* MS = (float*)Bs;          // mu[128], sc[128]
        const int half = wn >> 6;        // 0 or 1
        const int slot = half * 16 + lm;
        float bv[4];
        #pragma unroll
        for (int nt = 0; nt < 4; ++nt) bv[nt] = bias[wn + nt * 16 + lm];
        #pragma unroll
        for (int mt = 0; mt < 4; ++mt){
            #pragma unroll
            for (int r = 0; r < 4; ++r){
                int rl = wm + mt * 16 + lq * 4 + r;
                float ps = 0.f, pq = 0.f;
                #pragma unroll
                for (int nt = 0; nt < 4; ++nt){
                    float v = acc[mt][nt][r] + bv[nt];
                    ps += v; pq += v * v;
                }
                S1[rl * 32 + slot] = ps;
                S2[rl * 32 + slot] = pq;
            }
        }
        __syncthreads();
        if (tid < 128){
            float s = 0.f, sq = 0.f;
            #pragma unroll
            for (int j = 0; j < 32; ++j){
                s  += S1[tid * 32 + j];
                sq += S2[tid * 32 + j];
            }
            float mu = s * (1.0f / 128.0f);
            float var = sq * (1.0f / 128.0f) - mu * mu;
            MS[tid] = mu;
            MS[128 + tid] = rsqrtf(var + 1e-5f);
        }
        __syncthreads();
        float gv[4], bbv[4];
        #pragma unroll
        for (int nt = 0; nt < 4; ++nt){
            int col = wn + nt * 16 + lm;
            gv[nt] = g[col]; bbv[nt] = b[col];
        }
        #pragma unroll
        for (int mt = 0; mt < 4; ++mt){
            #pragma unroll
            for (int r = 0; r < 4; ++r){
                int rl = wm + mt * 16 + lq * 4 + r;
                int row = row0 + rl;
                if (row < M){
                    float mu = MS[rl], sc = MS[128 + rl];
                    #pragma unroll
                    for (int nt = 0; nt < 4; ++nt){
                        int col = wn + nt * 16 + lm;
                        float v = acc[mt][nt][r] + bv[nt];
                        float y = fmaxf((v - mu) * sc * gv[nt] + bbv[nt], 0.0f);
                        Ap[(size_t)row * 512 + col] = __float2bfloat16(y);
                    }
                }
            }
        }
    }
}

extern "C" void kernel_launch(void* const* d_in, const int* in_sizes, int n_in,
                              void* d_out, int out_size, void* d_ws, size_t ws_size,
                              hipStream_t stream) {
    const float* x     = (const float*)d_in[0];
    const int*   ei    = (const int*)d_in[1];
    const float* asp   = (const float*)d_in[2];
    const float* actx  = (const float*)d_in[3];
    const float* alat  = (const float*)d_in[4];
    const float* wsp   = (const float*)d_in[5];
    const float* wctx  = (const float*)d_in[6];
    const float* wlat  = (const float*)d_in[7];
    const float* W3    = (const float*)d_in[8];
    const float* Wself = (const float*)d_in[9];
    const float* bias  = (const float*)d_in[10];
    const float* dpow  = (const float*)d_in[11];
    const float* lng   = (const float*)d_in[12];
    const float* lnb   = (const float*)d_in[13];

    const int N = in_sizes[0] / 128;
    const int E = in_sizes[1] / 2;
    const int L = in_sizes[8] / (3 * 128 * 128);
    const int NB = cdiv(N, BK);
    const int* src = ei;
    const int* tgt = ei + E;

    // workspace carve (256B-aligned)
    char* p = (char*)d_ws;
    auto alloc = [&](size_t bytes) -> void* {
        void* r = (void*)p;
        p += (bytes + 255) & ~(size_t)255;
        return r;
    };
    int*   rs       = (int*)  alloc((size_t)(N + 1) * 4);
    int*   gcnt     = (int*)  alloc(1024 * 4);
    int*   bbase    = (int*)  alloc(1025 * 4);
    int*   gcur     = (int*)  alloc(1024 * 4);
    uint2* effo     = (uint2*)alloc((size_t)E * 8);
    uint2* nv       = (uint2*)alloc((size_t)L * E * 8);
    float* dinv_all = (float*)alloc((size_t)L * N * 3 * 4);
    __hip_bfloat16* Ap = (__hip_bfloat16*)alloc((size_t)N * 512 * 2);  // [x|Y0|Y1|Y2]
    __hip_bfloat16* BT = (__hip_bfloat16*)alloc((size_t)L * 128 * 512 * 2);
    uint4* binned = (uint4*)nv;  // aliased: binned (E*16B) dead before nv (L*E*8B) written

    // ---- prep: bucketed counting-sort CSR build ----
    hipMemsetAsync(gcnt, 0, 1024 * 4, stream);
    k_bcnt0 <<<cdiv(E, 4096), 256, 0, stream>>>(tgt, gcnt, E, NB);
    k_bscan <<<1, 256, 0, stream>>>(gcnt, bbase, gcur, rs, N, E);
    k_bin   <<<cdiv(E, 4096), 256, 0, stream>>>(src, tgt, asp, actx, alat, wsp, wctx, wlat,
                                                gcur, binned, E, NB);
    k_bucket<<<NB, 256, 0, stream>>>(binned, bbase, effo, rs, N);
    k_deg   <<<cdiv(N, 256), 256, 0, stream>>>(effo, rs, dpow, dinv_all, N, L);
    k_x2bf  <<<cdiv(N * 128, 256), 256, 0, stream>>>(x, Ap, N * 128);
    k_wcat  <<<cdiv(L * 65536, 256), 256, 0, stream>>>(Wself, W3, BT, L);
    k_normv <<<cdiv(L * E, 256), 256, 0, stream>>>(effo, dinv_all, nv, E, N, L);

    // ---- layers ----
    for (int l = 0; l < L; ++l){
        int doLN = (l < L - 1) ? 1 : 0;
        const float* dinv_l = dinv_all + (size_t)l * N * 3;
        k_msg <<<cdiv(N, 4), 256, 0, stream>>>(Ap, nv + (size_t)l * E, rs, dinv_l, N);
        k_gemm<<<cdiv(N, 128), 256, 0, stream>>>(Ap, BT + (size_t)l * 65536,
                                                 bias + l * 128, (float*)d_out, N,
                                                 doLN, lng, lnb, Ap);
    }
}